// Round 10
// baseline (234.785 us; speedup 1.0000x reference)
//
#include <hip/hip_runtime.h>
#include <math.h>

// ----------------------------------------------------------------------------
// Cross_Attention_Fourier collapses analytically:
//   fft2/ifft2 (ortho) around QK^T reduce to:  attn_c[q,l] = Q[q]·K[(N-l)%N]
//   => softmax(|Q·Kflip^T|) attention with V UNflipped (flip folded into K).
// R10: attn was latency-starved (Occ 9.5%, 45.7us, flat since R2). No-max
//     softmax => O,l are pure kv-sums => split kv 2x: 1024 blocks of the
//     16q/wave shape (49.4KB LDS, 3 blk/CU resident) write fp32 O/l partials;
//     k_comb merges halves + stats (film2 rides k_comb, not attn). 7 launches.
// ----------------------------------------------------------------------------

typedef _Float16 f16;
typedef _Float16 f16x4 __attribute__((ext_vector_type(4)));
typedef _Float16 f16x8 __attribute__((ext_vector_type(8)));
typedef float f32x4 __attribute__((ext_vector_type(4)));

#define ROWS 4096   // B*N = 4*1024
#define NTOK 1024
#define NB   4
#define NH   8
#define DH   64

__device__ __forceinline__ void glds16(const f16* g, f16* l) {
    __builtin_amdgcn_global_load_lds((const __attribute__((address_space(1))) void*)g,
                                     (__attribute__((address_space(3))) void*)l, 16, 0, 0);
}

struct PrepArgs { const float* src[6]; f16* dst[6]; };

// ---- LN helper: one wave, one 512-row --------------------------------------
__device__ __forceinline__ void ln_row(const float* __restrict__ x, const float* __restrict__ g,
                                       const float* __restrict__ bb, f16* __restrict__ o, int lane) {
    float v[8]; float s = 0.f;
#pragma unroll
    for (int j = 0; j < 8; j++) { v[j] = x[lane + 64 * j]; s += v[j]; }
#pragma unroll
    for (int d = 32; d >= 1; d >>= 1) s += __shfl_xor(s, d, 64);
    float mean = s * (1.f / 512.f);
    float q = 0.f;
#pragma unroll
    for (int j = 0; j < 8; j++) { float t = v[j] - mean; q += t * t; }
#pragma unroll
    for (int d = 32; d >= 1; d >>= 1) q += __shfl_xor(q, d, 64);
    float inv = rsqrtf(q * (1.f / 512.f) + 1e-5f);
#pragma unroll
    for (int j = 0; j < 8; j++) {
        int c = lane + 64 * j;
        o[c] = (f16)((v[j] - mean) * inv * g[c] + bb[c]);
    }
}

// ---- k_pre: init (0..47) | weight prep (48..1583) | LN (1584..3631) ---------
__global__ __launch_bounds__(256) void k_pre(PrepArgs pa, float* stats,
                                             const float* __restrict__ b_emd1, const float* __restrict__ b_emd2,
                                             float* __restrict__ tbacc, float* __restrict__ filmp,
                                             float* __restrict__ rstats,
                                             const float* __restrict__ diff, const float* __restrict__ g_dif,
                                             const float* __restrict__ b_dif, f16* __restrict__ A16,
                                             const float* __restrict__ con, const float* __restrict__ g_con,
                                             const float* __restrict__ b_con, f16* __restrict__ C16) {
    __shared__ float smem[1056];
    const int id = blockIdx.x, tid = threadIdx.x;
    if (id < 16) {
        int o = id * 256 + tid;                    // [0,4096)
        tbacc[o] = b_emd1[o & 1023];
        filmp[o] = b_emd2[o & 1023];
        if (id == 0 && tid < 8) stats[tid] = 0.f;
    } else if (id < 48) {
        rstats[(id - 16) * 256 + tid] = 0.f;       // 8192 floats
    } else if (id < 1584) {
        int pid = id - 48;
        int m = pid >> 8, rem = pid & 255;
        int o0 = (rem & 15) * 32, i0 = (rem >> 4) * 32;
        int tx = tid & 31, ty = tid >> 5;
        const float* src = pa.src[m];
        f16* dst = pa.dst[m];
        for (int r = ty; r < 32; r += 8)
            smem[r * 33 + tx] = src[(i0 + r) * 512 + o0 + tx];
        __syncthreads();
        for (int r = ty; r < 32; r += 8)
            dst[(o0 + r) * 512 + i0 + tx] = (f16)smem[tx * 33 + r];
    } else {
        int lane = tid & 63, wid = tid >> 6;
        long row = (long)(id - 1584) * 4 + wid;
        if (row < ROWS) ln_row(diff + row * 512, g_dif, b_dif, A16 + row * 512, lane);
        else { long r = row - ROWS; ln_row(con + r * 512, g_con, b_con, C16 + r * 512, lane); }
    }
}

// ---- k_qkv: qkv (0..767) | film1 split-K (768..831) -------------------------
// z=0: Qh[b][h][n][d]; z=1: Kf[b][h][flip(n)][d]; z=2: Vt[b][h][d][n]
__global__ __launch_bounds__(256) void k_qkv(const f16* __restrict__ A16, const f16* __restrict__ C16,
                                             const f16* __restrict__ wqT, const f16* __restrict__ wkT,
                                             const f16* __restrict__ wvT,
                                             f16* __restrict__ Qh, f16* __restrict__ Kf, f16* __restrict__ Vt,
                                             const float* __restrict__ temb, const float* __restrict__ w_emd1,
                                             float* __restrict__ tbacc) {
    __shared__ __attribute__((aligned(16))) f16 sh[128 * 128 + 64 * 128];   // 48 KB
    const int id = blockIdx.x, tid = threadIdx.x;
    if (id >= 768) {
        float* tsh = (float*)sh;   // [4][32]
        int pid = id - 768;
        int c = (pid & 3) * 256 + tid;
        int k0 = (pid >> 2) * 32;                  // 16 K-splits
        if (tid < 128) tsh[(tid >> 5) * 32 + (tid & 31)] = temb[(tid >> 5) * 512 + k0 + (tid & 31)];
        __syncthreads();
        float a0 = 0.f, a1 = 0.f, a2 = 0.f, a3 = 0.f;
#pragma unroll 8
        for (int k = 0; k < 32; k++) {
            float w = w_emd1[(k0 + k) * 1024 + c];
            a0 += tsh[k] * w; a1 += tsh[32 + k] * w; a2 += tsh[64 + k] * w; a3 += tsh[96 + k] * w;
        }
        atomicAdd(&tbacc[c], a0);        atomicAdd(&tbacc[1024 + c], a1);
        atomicAdd(&tbacc[2048 + c], a2); atomicAdd(&tbacc[3072 + c], a3);
        return;
    }
    f16* Ash = sh;
    f16* Bsh = sh + 128 * 128;
    const int z = id >> 8;
    const f16* A  = (z == 0) ? A16 : C16;
    const f16* BT = (z == 0) ? wqT : (z == 1) ? wkT : wvT;
    const int lane = tid & 63, wid = tid >> 6;
    const int quad = lane >> 4, l15 = lane & 15;
    const int m0 = (id & 31) * 128, n0 = ((id >> 5) & 7) * 64;
    const int wm = (wid >> 1) * 64, wn = (wid & 1) * 32;
    const int srow = lane >> 4, slot = lane & 15;
    f32x4 acc[4][2] = {};
    for (int kk = 0; kk < 512; kk += 128) {
        if (kk) __syncthreads();
#pragma unroll
        for (int c = 0; c < 8; c++) {
            int r = c * 16 + 4 * wid + srow;
            int j = slot ^ (r & 7);
            glds16(&A[(long)(m0 + r) * 512 + kk + 8 * j], &Ash[(c * 16 + 4 * wid) * 128]);
        }
#pragma unroll
        for (int c = 0; c < 4; c++) {
            int r = c * 16 + 4 * wid + srow;
            int j = slot ^ (r & 7);
            glds16(&BT[(long)(n0 + r) * 512 + kk + 8 * j], &Bsh[(c * 16 + 4 * wid) * 128]);
        }
        __syncthreads();
#pragma unroll
        for (int ks = 0; ks < 4; ks++) {
            const int rslot = ((ks * 4 + quad) ^ (l15 & 7)) * 8;
            f16x8 af[4], bf[2];
#pragma unroll
            for (int t = 0; t < 4; t++)
                af[t] = *(const f16x8*)&Ash[(wm + t * 16 + l15) * 128 + rslot];
#pragma unroll
            for (int t = 0; t < 2; t++)
                bf[t] = *(const f16x8*)&Bsh[(wn + t * 16 + l15) * 128 + rslot];
#pragma unroll
            for (int mt = 0; mt < 4; mt++)
#pragma unroll
                for (int nt = 0; nt < 2; nt++)
                    acc[mt][nt] = __builtin_amdgcn_mfma_f32_16x16x32_f16(af[mt], bf[nt], acc[mt][nt], 0, 0, 0);
        }
    }
    __syncthreads();
    const int bb = m0 >> 10, nn0 = m0 & 1023, h = (id >> 5) & 7;
    if (z <= 1) {
#pragma unroll
        for (int mt = 0; mt < 4; mt++)
#pragma unroll
            for (int nt = 0; nt < 2; nt++)
#pragma unroll
                for (int r = 0; r < 4; r++)
                    sh[(wm + mt * 16 + quad * 4 + r) * 72 + wn + nt * 16 + l15] = (f16)acc[mt][nt][r];
        __syncthreads();
        f16* dst = (z == 0) ? Qh : Kf;
        long basebh = ((long)(bb * NH + h)) * NTOK * DH;
#pragma unroll
        for (int q2 = 0; q2 < 4; q2++) {
            int c = tid + q2 * 256;
            int row = c >> 3, col = (c & 7) * 8;
            int n = nn0 + row;
            int nr = (z == 1) ? ((NTOK - n) & (NTOK - 1)) : n;
            *(f16x8*)&dst[basebh + (long)nr * DH + col] = *(const f16x8*)&sh[row * 72 + col];
        }
    } else {
#pragma unroll
        for (int mt = 0; mt < 4; mt++)
#pragma unroll
            for (int nt = 0; nt < 2; nt++)
#pragma unroll
                for (int r = 0; r < 4; r++)
                    sh[(wn + nt * 16 + l15) * 136 + wm + mt * 16 + quad * 4 + r] = (f16)acc[mt][nt][r];
        __syncthreads();
        long basev = ((long)(bb * NH + h)) * DH * NTOK;
#pragma unroll
        for (int q2 = 0; q2 < 4; q2++) {
            int c = tid + q2 * 256;
            int d = c >> 4, col = (c & 15) * 8;
            *(f16x8*)&Vt[basev + (long)d * NTOK + nn0 + col] = *(const f16x8*)&sh[d * 136 + col];
        }
    }
}

// ---- k_attn: kv-SPLIT flash attention, 16q/wave, fp32 partial O + l ---------
// grid 1024: bh = id&31 (XCD cluster), qt = (id>>5)&15, half = id>>9.
// S^T = Kf·Q^T (lane holds 4 consecutive kv of one q-col -> b64 P-writes);
// P = exp(|S|-8) (shift-invariant, no max); O,l are pure kv-sums -> partials.
__global__ __launch_bounds__(256) void k_attn(const f16* __restrict__ Q, const f16* __restrict__ Kf,
                                              const f16* __restrict__ Vt,
                                              float* __restrict__ Opart, float* __restrict__ lpart) {
    __shared__ __attribute__((aligned(16))) f16 Ksh[128 * 64];
    __shared__ __attribute__((aligned(16))) f16 Vsh[64 * 128];
    __shared__ __attribute__((aligned(16))) f16 PshT[4 * 16 * 136];
    const int id = blockIdx.x, tid = threadIdx.x;
    const int lane = tid & 63, wid = tid >> 6;
    const int quad = lane >> 4, l15 = lane & 15;
    const int bh = id & 31;
    const int rest = id >> 5;
    const int qt = rest & 15, half = rest >> 4;
    const int b = bh >> 3, hh = bh & 7, q0 = qt * 64;
    const int kbase = half * 512;
    const f16* Qbh = Q + (long)bh * NTOK * DH;
    const f16* Kbh = Kf + (long)bh * NTOK * DH;
    const f16* Vbh = Vt + (long)bh * DH * NTOK;
    const int rl = lane >> 3, jj8 = (lane & 7) ^ rl;                 // K swizzle
    const int rl4 = lane >> 4, jjv = (lane & 15) ^ (4 * wid + rl4);  // V swizzle
    const int qrow = q0 + wid * 16 + l15;
    f16x8 qf[2];
    qf[0] = *(const f16x8*)&Qbh[(long)qrow * DH + quad * 8];
    qf[1] = *(const f16x8*)&Qbh[(long)qrow * DH + 32 + quad * 8];
    f32x4 O[4] = {};
    float l_acc = 0.f;                    // partial row-sum for q = l15 (this wave)
    f16* Pw = PshT + wid * 16 * 136;      // wave-local P^T region [q][kv]

    for (int k0 = 0; k0 < 512; k0 += 128) {
        if (k0) __syncthreads();
        const int kb = kbase + k0;
#pragma unroll
        for (int c = 0; c < 4; c++) {
            int rk = c * 32 + 8 * wid + rl;
            glds16(&Kbh[(long)(kb + rk) * DH + 8 * jj8], &Ksh[(c * 32 + 8 * wid) * 64]);
        }
#pragma unroll
        for (int c = 0; c < 4; c++) {
            int rv = c * 16 + 4 * wid + rl4;
            glds16(&Vbh[(long)rv * NTOK + kb + 8 * jjv], &Vsh[(c * 16 + 4 * wid) * 128]);
        }
        __syncthreads();
        // S^T(128kv x 16q) = Kf · Q^T : lane holds S[q=l15][kv=16nt+quad*4+r]
        f32x4 st[8] = {};
#pragma unroll
        for (int ks = 0; ks < 2; ks++) {
            const int slot = ((ks * 4 + quad) ^ (l15 & 7)) * 8;
#pragma unroll
            for (int nt = 0; nt < 8; nt++) {
                f16x8 kf = *(const f16x8*)&Ksh[(nt * 16 + l15) * 64 + slot];
                st[nt] = __builtin_amdgcn_mfma_f32_16x16x32_f16(kf, qf[ks], st[nt], 0, 0, 0);
            }
        }
        // P = exp(|S|-8) (shift-invariant; |S|max~9.4 << 19); packed b64 writes
#pragma unroll
        for (int nt = 0; nt < 8; nt++) {
            float p0 = __expf(fminf(fabsf(st[nt][0]) - 8.f, 11.f));
            float p1 = __expf(fminf(fabsf(st[nt][1]) - 8.f, 11.f));
            float p2 = __expf(fminf(fabsf(st[nt][2]) - 8.f, 11.f));
            float p3 = __expf(fminf(fabsf(st[nt][3]) - 8.f, 11.f));
            l_acc += (p0 + p1) + (p2 + p3);
            f16x4 pk = { (f16)p0, (f16)p1, (f16)p2, (f16)p3 };
            *(f16x4*)&Pw[l15 * 136 + 16 * nt + quad * 4] = pk;   // wave-local, no barrier
        }
        // O(16q x 64d) += P @ V
#pragma unroll
        for (int ks = 0; ks < 4; ks++) {
            f16x8 pf = *(const f16x8*)&Pw[l15 * 136 + 32 * ks + quad * 8];
            const int vslot = ((ks * 4 + quad) ^ l15) * 8;
#pragma unroll
            for (int vt = 0; vt < 4; vt++) {
                f16x8 vf = *(const f16x8*)&Vsh[(vt * 16 + l15) * 128 + vslot];
                O[vt] = __builtin_amdgcn_mfma_f32_16x16x32_f16(pf, vf, O[vt], 0, 0, 0);
            }
        }
    }
    // l partial: sum quads; all quads hold q=l15 value -> quad 0 stores (coalesced)
    l_acc += __shfl_xor(l_acc, 16, 64);
    l_acc += __shfl_xor(l_acc, 32, 64);
    if (quad == 0) lpart[half * (32 * NTOK) + bh * NTOK + qrow] = l_acc;
    // O partial: fp32 unnormalized
    float* Od = Opart + (size_t)half * ROWS * 512;
#pragma unroll
    for (int t = 0; t < 4; t++)
#pragma unroll
        for (int r = 0; r < 4; r++) {
            int gn = q0 + wid * 16 + quad * 4 + r;
            int gc = hh * DH + t * 16 + l15;
            Od[((long)b * NTOK + gn) * 512 + gc] = O[t][r];
        }
}

// ---- k_comb: combine kv-halves + batch stats (0..2047) | film2 (2048..2175) -
__global__ __launch_bounds__(256) void k_comb(const float* __restrict__ Opart, const float* __restrict__ lpart,
                                              f16* __restrict__ aout16, float* __restrict__ stats,
                                              const float* __restrict__ tbacc, const float* __restrict__ w_emd2,
                                              float* __restrict__ filmp) {
    __shared__ float tsh[128];
    __shared__ float rbuf[8];
    const int id = blockIdx.x, tid = threadIdx.x;
    if (id >= 2048) {
        // FiLM layer 2 split-K: filmp[b][c] += silu(tbacc[b][k])·w2[k][c]
        int pid = id - 2048;
        int c = (pid & 3) * 256 + tid;
        int k0 = (pid >> 2) * 32;                  // 32 K-splits
        if (tid < 128) {
            float v = tbacc[(tid >> 5) * 1024 + k0 + (tid & 31)];
            tsh[(tid >> 5) * 32 + (tid & 31)] = v / (1.f + __expf(-v));   // silu
        }
        __syncthreads();
        float a0 = 0.f, a1 = 0.f, a2 = 0.f, a3 = 0.f;
#pragma unroll 8
        for (int k = 0; k < 32; k++) {
            float w = w_emd2[(k0 + k) * 1024 + c];
            a0 += tsh[k] * w; a1 += tsh[32 + k] * w; a2 += tsh[64 + k] * w; a3 += tsh[96 + k] * w;
        }
        atomicAdd(&filmp[c], a0);        atomicAdd(&filmp[1024 + c], a1);
        atomicAdd(&filmp[2048 + c], a2); atomicAdd(&filmp[3072 + c], a3);
        return;
    }
    const int lane = tid & 63, wid = tid >> 6;
    long base = ((long)id * 256 + tid) * 4;
    int b = (int)(base >> 19);
    int row = (int)(base >> 9);                    // b*1024 + n
    int n = row & 1023;
    int col = (int)(base & 511);
    int h = col >> 6;
    int bhn = (b * 8 + h) * NTOK + n;
    float4 o0 = *(const float4*)&Opart[base];
    float4 o1 = *(const float4*)&Opart[(size_t)ROWS * 512 + base];
    float fr = 0.125f / (lpart[bhn] + lpart[32 * NTOK + bhn]);
    float v0 = (o0.x + o1.x) * fr, v1 = (o0.y + o1.y) * fr;
    float v2 = (o0.z + o1.z) * fr, v3 = (o0.w + o1.w) * fr;
    f16x4 pk = { (f16)v0, (f16)v1, (f16)v2, (f16)v3 };
    *(f16x4*)&aout16[base] = pk;
    float lsum = (v0 + v1) + (v2 + v3);
    float lsq = (v0 * v0 + v1 * v1) + (v2 * v2 + v3 * v3);
#pragma unroll
    for (int d = 32; d >= 1; d >>= 1) { lsum += __shfl_xor(lsum, d, 64); lsq += __shfl_xor(lsq, d, 64); }
    if (lane == 0) { rbuf[wid] = lsum; rbuf[4 + wid] = lsq; }
    __syncthreads();
    if (tid == 0) {
        atomicAdd(&stats[b * 2], rbuf[0] + rbuf[1] + rbuf[2] + rbuf[3]);
        atomicAdd(&stats[b * 2 + 1], rbuf[4] + rbuf[5] + rbuf[6] + rbuf[7]);
    }
}

// ---- gemm2 + fused global-norm/FiLM on A; emits fp16 out1 + row stats -------
__global__ __launch_bounds__(256) void k_gemm2f(const f16* __restrict__ aout16, const float* __restrict__ stats,
                                                const float* __restrict__ filmp,
                                                const f16* __restrict__ BT, const float* __restrict__ bias,
                                                f16* __restrict__ out1h, float* __restrict__ rstats) {
    __shared__ __attribute__((aligned(16))) f16 Ash[64 * 128];
    __shared__ __attribute__((aligned(16))) f16 Bsh[64 * 128];
    __shared__ float scsh[512], shsh[512];
    const int tid = threadIdx.x;
    const int lane = tid & 63, wid = tid >> 6;
    const int quad = lane >> 4, l15 = lane & 15;
    const int m0 = blockIdx.x * 64, n0 = blockIdx.y * 64;
    const int wm = (wid >> 1) * 32, wn = (wid & 1) * 32;
    const int srow = lane >> 4, slot = lane & 15;
    const int b = m0 >> 10;
    {   // per-column scale/shift table (batch-wide stats)
        float sum = stats[b * 2], sq = stats[b * 2 + 1];
        const float M = 524288.f;
        float mu = sum / M;
        float isd = rsqrtf((sq - sum * mu) / (M - 1.f));   // torch.std ddof=1
        for (int c = tid; c < 512; c += 256) {
            float sc = isd * filmp[b * 1024 + 512 + c];
            scsh[c] = sc;
            shsh[c] = filmp[b * 1024 + c] - mu * sc;
        }
    }
    __syncthreads();
    f32x4 acc[2][2] = {};
    for (int kk = 0; kk < 512; kk += 128) {
        if (kk) __syncthreads();
        const int j = slot ^ ((4 * wid + srow) & 7);   // constant per thread
        const int gcol = kk + 8 * j;
        float sc[8], sf[8];
        *(float4*)&sc[0] = *(const float4*)&scsh[gcol];
        *(float4*)&sc[4] = *(const float4*)&scsh[gcol + 4];
        *(float4*)&sf[0] = *(const float4*)&shsh[gcol];
        *(float4*)&sf[4] = *(const float4*)&shsh[gcol + 4];
#pragma unroll
        for (int c = 0; c < 4; c++) {
            int r = c * 16 + 4 * wid + srow;
            f16x8 v = *(const f16x8*)&aout16[(long)(m0 + r) * 512 + gcol];
            f16x8 y;
#pragma unroll
            for (int e = 0; e < 8; e++) y[e] = (f16)((float)v[e] * sc[e] + sf[e]);
            *(f16x8*)&Ash[(c * 16 + 4 * wid) * 128 + lane * 8] = y;
            glds16(&BT[(long)(n0 + r) * 512 + kk + 8 * j], &Bsh[(c * 16 + 4 * wid) * 128]);
        }
        __syncthreads();
#pragma unroll
        for (int ks = 0; ks < 4; ks++) {
            const int rslot = ((ks * 4 + quad) ^ (l15 & 7)) * 8;
            f16x8 af[2], bf[2];
#pragma unroll
            for (int t = 0; t < 2; t++) {
                af[t] = *(const f16x8*)&Ash[(wm + t * 16 + l15) * 128 + rslot];
                bf[t] = *(const f16x8*)&Bsh[(wn + t * 16 + l15) * 128 + rslot];
            }
#pragma unroll
            for (int mt = 0; mt < 2; mt++)
#pragma unroll
                for (int nt = 0; nt < 2; nt++)
                    acc[mt][nt] = __builtin_amdgcn_mfma_f32_16x16x32_f16(af[mt], bf[nt], acc[mt][nt], 0, 0, 0);
        }
    }
    // epilogue: +bias, fp16 store, per-row sum/sumsq partials -> rstats
#pragma unroll
    for (int mt = 0; mt < 2; mt++)
#pragma unroll
        for (int r = 0; r < 4; r++) {
            int gm = m0 + wm + mt * 16 + quad * 4 + r;
            float v0 = acc[mt][0][r] + bias[n0 + wn + l15];
            float v1 = acc[mt][1][r] + bias[n0 + wn + 16 + l15];
            out1h[(long)gm * 512 + n0 + wn + l15] = (f16)v0;
            out1h[(long)gm * 512 + n0 + wn + 16 + l15] = (f16)v1;
            float s = v0 + v1, q2 = v0 * v0 + v1 * v1;
#pragma unroll
            for (int d = 8; d >= 1; d >>= 1) { s += __shfl_xor(s, d, 16); q2 += __shfl_xor(q2, d, 16); }
            if (l15 == 0) {
                atomicAdd(&rstats[gm * 2], s);
                atomicAdd(&rstats[gm * 2 + 1], q2);
            }
        }
}

// ---- gemm3 with fused LayerNorm on A (row mu/inv + col g/b), GELU out -------
__global__ __launch_bounds__(256) void k_gemm3f(const f16* __restrict__ out1h, const float* __restrict__ rstats,
                                                const float* __restrict__ lng, const float* __restrict__ lnb,
                                                const f16* __restrict__ BT, const float* __restrict__ bias,
                                                f16* __restrict__ X4) {
    __shared__ __attribute__((aligned(16))) f16 Ash[64 * 128];
    __shared__ __attribute__((aligned(16))) f16 Bsh[64 * 128];
    __shared__ float musr[64], invsr[64], gsh[512], bsh[512];
    const int tid = threadIdx.x;
    const int lane = tid & 63, wid = tid >> 6;
    const int quad = lane >> 4, l15 = lane & 15;
    const int m0 = blockIdx.x * 64, n0 = blockIdx.y * 64;
    const int wm = (wid >> 1) * 32, wn = (wid & 1) * 32;
    const int srow = lane >> 4, slot = lane & 15;
    if (tid < 64) {
        float s = rstats[(m0 + tid) * 2], sq = rstats[(m0 + tid) * 2 + 1];
        float mu = s * (1.f / 512.f);
        float var = sq * (1.f / 512.f) - mu * mu;
        musr[tid] = mu;
        invsr[tid] = rsqrtf(var + 1e-5f);
    }
    for (int i = tid; i < 512; i += 256) { gsh[i] = lng[i]; bsh[i] = lnb[i]; }
    __syncthreads();
    f32x4 acc[2][2] = {};
    for (int kk = 0; kk < 512; kk += 128) {
        if (kk) __syncthreads();
        const int j = slot ^ ((4 * wid + srow) & 7);   // constant per thread
        const int gcol = kk + 8 * j;
        float gv[8], bv[8];
        *(float4*)&gv[0] = *(const float4*)&gsh[gcol];
        *(float4*)&gv[4] = *(const float4*)&gsh[gcol + 4];
        *(float4*)&bv[0] = *(const float4*)&bsh[gcol];
        *(float4*)&bv[4] = *(const float4*)&bsh[gcol + 4];
#pragma unroll
        for (int c = 0; c < 4; c++) {
            int r = c * 16 + 4 * wid + srow;
            f16x8 x = *(const f16x8*)&out1h[(long)(m0 + r) * 512 + gcol];
            float a = invsr[r], m = musr[r];
            f16x8 y;
#pragma unroll
            for (int e = 0; e < 8; e++) {
                float sc = a * gv[e];
                y[e] = (f16)((float)x[e] * sc + (bv[e] - m * sc));
            }
            *(f16x8*)&Ash[(c * 16 + 4 * wid) * 128 + lane * 8] = y;
            glds16(&BT[(long)(n0 + r) * 512 + kk + 8 * j], &Bsh[(c * 16 + 4 * wid) * 128]);
        }
        __syncthreads();
#pragma unroll
        for (int ks = 0; ks < 4; ks++) {
            const int rslot = ((ks * 4 + quad) ^ (l15 & 7)) * 8;
            f16x8 af[2], bf[2];
#pragma unroll
            for (int t = 0; t < 2; t++) {
                af[t] = *(const f16x8*)&Ash[(wm + t * 16 + l15) * 128 + rslot];
                bf[t] = *(const f16x8*)&Bsh[(wn + t * 16 + l15) * 128 + rslot];
            }
#pragma unroll
            for (int mt = 0; mt < 2; mt++)
#pragma unroll
                for (int nt = 0; nt < 2; nt++)
                    acc[mt][nt] = __builtin_amdgcn_mfma_f32_16x16x32_f16(af[mt], bf[nt], acc[mt][nt], 0, 0, 0);
        }
    }
#pragma unroll
    for (int mt = 0; mt < 2; mt++)
#pragma unroll
        for (int nt = 0; nt < 2; nt++)
#pragma unroll
            for (int r = 0; r < 4; r++) {
                int gm = m0 + wm + mt * 16 + quad * 4 + r;
                int gn = n0 + wn + nt * 16 + l15;
                float x = acc[mt][nt][r] + bias[gn];
                X4[(long)gm * 512 + gn] = (f16)(0.5f * x * (1.0f + erff(x * 0.70710678f)));
            }
}

// ---- 64x64-tile GEMM, BK=128, glds+swizzle (final: +bias fp32) --------------
__global__ __launch_bounds__(256) void k_gemm4(const f16* __restrict__ A, const f16* __restrict__ BT,
                                               const float* __restrict__ bias, float* __restrict__ dst) {
    __shared__ __attribute__((aligned(16))) f16 Ash[64 * 128];
    __shared__ __attribute__((aligned(16))) f16 Bsh[64 * 128];
    const int tid = threadIdx.x;
    const int lane = tid & 63, wid = tid >> 6;
    const int quad = lane >> 4, l15 = lane & 15;
    const int m0 = blockIdx.x * 64, n0 = blockIdx.y * 64;
    const int wm = (wid >> 1) * 32, wn = (wid & 1) * 32;
    const int srow = lane >> 4, slot = lane & 15;
    f32x4 acc[2][2] = {};
    for (int kk = 0; kk < 512; kk += 128) {
        if (kk) __syncthreads();
#pragma unroll
        for (int c = 0; c < 4; c++) {
            int r = c * 16 + 4 * wid + srow;
            int j = slot ^ (r & 7);
            glds16(&A[(long)(m0 + r) * 512 + kk + 8 * j], &Ash[(c * 16 + 4 * wid) * 128]);
            glds16(&BT[(long)(n0 + r) * 512 + kk + 8 * j], &Bsh[(c * 16 + 4 * wid) * 128]);
        }
        __syncthreads();
#pragma unroll
        for (int ks = 0; ks < 4; ks++) {
            const int rslot = ((ks * 4 + quad) ^ (l15 & 7)) * 8;
            f16x8 af[2], bf[2];
#pragma unroll
            for (int t = 0; t < 2; t++) {
                af[t] = *(const f16x8*)&Ash[(wm + t * 16 + l15) * 128 + rslot];
                bf[t] = *(const f16x8*)&Bsh[(wn + t * 16 + l15) * 128 + rslot];
            }
#pragma unroll
            for (int mt = 0; mt < 2; mt++)
#pragma unroll
                for (int nt = 0; nt < 2; nt++)
                    acc[mt][nt] = __builtin_amdgcn_mfma_f32_16x16x32_f16(af[mt], bf[nt], acc[mt][nt], 0, 0, 0);
        }
    }
#pragma unroll
    for (int mt = 0; mt < 2; mt++)
#pragma unroll
        for (int nt = 0; nt < 2; nt++)
#pragma unroll
            for (int r = 0; r < 4; r++) {
                int gm = m0 + wm + mt * 16 + quad * 4 + r;
                int gn = n0 + wn + nt * 16 + l15;
                dst[(long)gm * 512 + gn] = acc[mt][nt][r] + bias[gn];
            }
}

// ----------------------------------------------------------------------------
extern "C" void kernel_launch(void* const* d_in, const int* in_sizes, int n_in,
                              void* d_out, int out_size, void* d_ws, size_t ws_size,
                              hipStream_t stream) {
    const float* con      = (const float*)d_in[0];
    const float* diff     = (const float*)d_in[1];
    const float* temb     = (const float*)d_in[2];
    const float* ln_con_g = (const float*)d_in[3];
    const float* ln_con_b = (const float*)d_in[4];
    const float* ln_dif_g = (const float*)d_in[5];
    const float* ln_dif_b = (const float*)d_in[6];
    const float* wq       = (const float*)d_in[7];
    const float* wk       = (const float*)d_in[8];
    const float* wv       = (const float*)d_in[9];
    const float* w_out    = (const float*)d_in[10];
    const float* b_out    = (const float*)d_in[11];
    const float* w_emd1   = (const float*)d_in[12];
    const float* b_emd1   = (const float*)d_in[13];
    const float* w_emd2   = (const float*)d_in[14];
    const float* b_emd2   = (const float*)d_in[15];
    const float* mlp_ln_g = (const float*)d_in[16];
    const float* mlp_ln_b = (const float*)d_in[17];
    const float* mlp_w1   = (const float*)d_in[18];
    const float* mlp_b1   = (const float*)d_in[19];
    const float* mlp_w2   = (const float*)d_in[20];
    const float* mlp_b2   = (const float*)d_in[21];
    float* outp = (float*)d_out;

    char* ws = (char*)d_ws;
    size_t off = 0;
    auto alloc = [&](size_t bytes) { void* p = ws + off; off += (bytes + 255) & ~(size_t)255; return p; };
    f16*   A16   = (f16*)alloc((size_t)ROWS * 512 * 2);   // LN(diff)
    f16*   C16   = (f16*)alloc((size_t)ROWS * 512 * 2);   // LN(con); later X4
    f16*   Qh    = (f16*)alloc((size_t)ROWS * 512 * 2);   // later out1h
    f16*   Kf    = (f16*)alloc((size_t)ROWS * 512 * 2);
    f16*   Vt    = (f16*)alloc((size_t)ROWS * 512 * 2);
    f16*   aout16= (f16*)alloc((size_t)ROWS * 512 * 2);   // combined attn out, fp16
    float* Opart = (float*)alloc((size_t)2 * ROWS * 512 * 4);   // kv-split partials
    float* lpart = (float*)alloc((size_t)2 * 32 * NTOK * 4);
    f16*   wqT   = (f16*)alloc(512 * 512 * 2);
    f16*   wkT   = (f16*)alloc(512 * 512 * 2);
    f16*   wvT   = (f16*)alloc(512 * 512 * 2);
    f16*   woT   = (f16*)alloc(512 * 512 * 2);
    f16*   w1T   = (f16*)alloc(512 * 512 * 2);
    f16*   w2T   = (f16*)alloc(512 * 512 * 2);
    float* tbacc = (float*)alloc(4 * 1024 * 4);
    float* filmp = (float*)alloc(4 * 1024 * 4);
    float* stats = (float*)alloc(256);
    float* rstats= (float*)alloc(ROWS * 2 * 4);
    f16*   out1h = Qh;    // overlay (Qh dead after attn)
    f16*   X4    = C16;   // overlay (C16 dead after qkv)

    PrepArgs pa;
    pa.src[0] = wq;  pa.src[1] = wk;  pa.src[2] = wv;
    pa.src[3] = w_out; pa.src[4] = mlp_w1; pa.src[5] = mlp_w2;
    pa.dst[0] = wqT; pa.dst[1] = wkT; pa.dst[2] = wvT;
    pa.dst[3] = woT; pa.dst[4] = w1T; pa.dst[5] = w2T;

    k_pre<<<dim3(3632), dim3(256), 0, stream>>>(pa, stats, b_emd1, b_emd2, tbacc, filmp, rstats,
                                                diff, ln_dif_g, ln_dif_b, A16,
                                                con, ln_con_g, ln_con_b, C16);
    k_qkv<<<dim3(832), dim3(256), 0, stream>>>(A16, C16, wqT, wkT, wvT, Qh, Kf, Vt,
                                               temb, w_emd1, tbacc);
    k_attn<<<dim3(1024), dim3(256), 0, stream>>>(Qh, Kf, Vt, Opart, lpart);
    k_comb<<<dim3(2176), dim3(256), 0, stream>>>(Opart, lpart, aout16, stats,
                                                 tbacc, w_emd2, filmp);
    k_gemm2f<<<dim3(64, 8), dim3(256), 0, stream>>>(aout16, stats, filmp, woT, b_out, out1h, rstats);
    k_gemm3f<<<dim3(64, 8), dim3(256), 0, stream>>>(out1h, rstats, mlp_ln_g, mlp_ln_b, w1T, mlp_b1, X4);
    k_gemm4<<<dim3(64, 8), dim3(256), 0, stream>>>(X4, w2T, mlp_b2, outp);
}

// Round 11
// 181.906 us; speedup vs baseline: 1.2907x; 1.2907x over previous
//
#include <hip/hip_runtime.h>
#include <math.h>

// ----------------------------------------------------------------------------
// Cross_Attention_Fourier collapses analytically:
//   fft2/ifft2 (ortho) around QK^T reduce to:  attn_c[q,l] = Q[q]·K[(N-l)%N]
//   => softmax(|Q·Kflip^T|) attention with V UNflipped (flip folded into K).
// R11: R10's k_comb spent 58us on 4096 device atomics to ONE cacheline
//     (stats[8]) — cross-XCD RMW serialization ~14ns each. Fix: spread the
//     batch-stats reduction over 64 padded slots (statsp[64][16]); gemm2f
//     shuffle-reduces the 64 partials. kv-split attn kept. 7 launches.
// ----------------------------------------------------------------------------

typedef _Float16 f16;
typedef _Float16 f16x4 __attribute__((ext_vector_type(4)));
typedef _Float16 f16x8 __attribute__((ext_vector_type(8)));
typedef float f32x4 __attribute__((ext_vector_type(4)));

#define ROWS 4096   // B*N = 4*1024
#define NTOK 1024
#define NB   4
#define NH   8
#define DH   64

__device__ __forceinline__ void glds16(const f16* g, f16* l) {
    __builtin_amdgcn_global_load_lds((const __attribute__((address_space(1))) void*)g,
                                     (__attribute__((address_space(3))) void*)l, 16, 0, 0);
}

struct PrepArgs { const float* src[6]; f16* dst[6]; };

// ---- LN helper: one wave, one 512-row --------------------------------------
__device__ __forceinline__ void ln_row(const float* __restrict__ x, const float* __restrict__ g,
                                       const float* __restrict__ bb, f16* __restrict__ o, int lane) {
    float v[8]; float s = 0.f;
#pragma unroll
    for (int j = 0; j < 8; j++) { v[j] = x[lane + 64 * j]; s += v[j]; }
#pragma unroll
    for (int d = 32; d >= 1; d >>= 1) s += __shfl_xor(s, d, 64);
    float mean = s * (1.f / 512.f);
    float q = 0.f;
#pragma unroll
    for (int j = 0; j < 8; j++) { float t = v[j] - mean; q += t * t; }
#pragma unroll
    for (int d = 32; d >= 1; d >>= 1) q += __shfl_xor(q, d, 64);
    float inv = rsqrtf(q * (1.f / 512.f) + 1e-5f);
#pragma unroll
    for (int j = 0; j < 8; j++) {
        int c = lane + 64 * j;
        o[c] = (f16)((v[j] - mean) * inv * g[c] + bb[c]);
    }
}

// ---- k_pre: init (0..47) | weight prep (48..1583) | LN (1584..3631) ---------
__global__ __launch_bounds__(256) void k_pre(PrepArgs pa, float* statsp,
                                             const float* __restrict__ b_emd1, const float* __restrict__ b_emd2,
                                             float* __restrict__ tbacc, float* __restrict__ filmp,
                                             float* __restrict__ rstats,
                                             const float* __restrict__ diff, const float* __restrict__ g_dif,
                                             const float* __restrict__ b_dif, f16* __restrict__ A16,
                                             const float* __restrict__ con, const float* __restrict__ g_con,
                                             const float* __restrict__ b_con, f16* __restrict__ C16) {
    __shared__ float smem[1056];
    const int id = blockIdx.x, tid = threadIdx.x;
    if (id < 16) {
        int o = id * 256 + tid;                    // [0,4096)
        tbacc[o] = b_emd1[o & 1023];
        filmp[o] = b_emd2[o & 1023];
        if (id < 4) statsp[id * 256 + tid] = 0.f;  // 64 slots x 16 floats
    } else if (id < 48) {
        rstats[(id - 16) * 256 + tid] = 0.f;       // 8192 floats
    } else if (id < 1584) {
        int pid = id - 48;
        int m = pid >> 8, rem = pid & 255;
        int o0 = (rem & 15) * 32, i0 = (rem >> 4) * 32;
        int tx = tid & 31, ty = tid >> 5;
        const float* src = pa.src[m];
        f16* dst = pa.dst[m];
        for (int r = ty; r < 32; r += 8)
            smem[r * 33 + tx] = src[(i0 + r) * 512 + o0 + tx];
        __syncthreads();
        for (int r = ty; r < 32; r += 8)
            dst[(o0 + r) * 512 + i0 + tx] = (f16)smem[tx * 33 + r];
    } else {
        int lane = tid & 63, wid = tid >> 6;
        long row = (long)(id - 1584) * 4 + wid;
        if (row < ROWS) ln_row(diff + row * 512, g_dif, b_dif, A16 + row * 512, lane);
        else { long r = row - ROWS; ln_row(con + r * 512, g_con, b_con, C16 + r * 512, lane); }
    }
}

// ---- k_qkv: qkv (0..767) | film1 split-K (768..831) -------------------------
// z=0: Qh[b][h][n][d]; z=1: Kf[b][h][flip(n)][d]; z=2: Vt[b][h][d][n]
__global__ __launch_bounds__(256) void k_qkv(const f16* __restrict__ A16, const f16* __restrict__ C16,
                                             const f16* __restrict__ wqT, const f16* __restrict__ wkT,
                                             const f16* __restrict__ wvT,
                                             f16* __restrict__ Qh, f16* __restrict__ Kf, f16* __restrict__ Vt,
                                             const float* __restrict__ temb, const float* __restrict__ w_emd1,
                                             float* __restrict__ tbacc) {
    __shared__ __attribute__((aligned(16))) f16 sh[128 * 128 + 64 * 128];   // 48 KB
    const int id = blockIdx.x, tid = threadIdx.x;
    if (id >= 768) {
        float* tsh = (float*)sh;   // [4][32]
        int pid = id - 768;
        int c = (pid & 3) * 256 + tid;
        int k0 = (pid >> 2) * 32;                  // 16 K-splits
        if (tid < 128) tsh[(tid >> 5) * 32 + (tid & 31)] = temb[(tid >> 5) * 512 + k0 + (tid & 31)];
        __syncthreads();
        float a0 = 0.f, a1 = 0.f, a2 = 0.f, a3 = 0.f;
#pragma unroll 8
        for (int k = 0; k < 32; k++) {
            float w = w_emd1[(k0 + k) * 1024 + c];
            a0 += tsh[k] * w; a1 += tsh[32 + k] * w; a2 += tsh[64 + k] * w; a3 += tsh[96 + k] * w;
        }
        atomicAdd(&tbacc[c], a0);        atomicAdd(&tbacc[1024 + c], a1);
        atomicAdd(&tbacc[2048 + c], a2); atomicAdd(&tbacc[3072 + c], a3);
        return;
    }
    f16* Ash = sh;
    f16* Bsh = sh + 128 * 128;
    const int z = id >> 8;
    const f16* A  = (z == 0) ? A16 : C16;
    const f16* BT = (z == 0) ? wqT : (z == 1) ? wkT : wvT;
    const int lane = tid & 63, wid = tid >> 6;
    const int quad = lane >> 4, l15 = lane & 15;
    const int m0 = (id & 31) * 128, n0 = ((id >> 5) & 7) * 64;
    const int wm = (wid >> 1) * 64, wn = (wid & 1) * 32;
    const int srow = lane >> 4, slot = lane & 15;
    f32x4 acc[4][2] = {};
    for (int kk = 0; kk < 512; kk += 128) {
        if (kk) __syncthreads();
#pragma unroll
        for (int c = 0; c < 8; c++) {
            int r = c * 16 + 4 * wid + srow;
            int j = slot ^ (r & 7);
            glds16(&A[(long)(m0 + r) * 512 + kk + 8 * j], &Ash[(c * 16 + 4 * wid) * 128]);
        }
#pragma unroll
        for (int c = 0; c < 4; c++) {
            int r = c * 16 + 4 * wid + srow;
            int j = slot ^ (r & 7);
            glds16(&BT[(long)(n0 + r) * 512 + kk + 8 * j], &Bsh[(c * 16 + 4 * wid) * 128]);
        }
        __syncthreads();
#pragma unroll
        for (int ks = 0; ks < 4; ks++) {
            const int rslot = ((ks * 4 + quad) ^ (l15 & 7)) * 8;
            f16x8 af[4], bf[2];
#pragma unroll
            for (int t = 0; t < 4; t++)
                af[t] = *(const f16x8*)&Ash[(wm + t * 16 + l15) * 128 + rslot];
#pragma unroll
            for (int t = 0; t < 2; t++)
                bf[t] = *(const f16x8*)&Bsh[(wn + t * 16 + l15) * 128 + rslot];
#pragma unroll
            for (int mt = 0; mt < 4; mt++)
#pragma unroll
                for (int nt = 0; nt < 2; nt++)
                    acc[mt][nt] = __builtin_amdgcn_mfma_f32_16x16x32_f16(af[mt], bf[nt], acc[mt][nt], 0, 0, 0);
        }
    }
    __syncthreads();
    const int bb = m0 >> 10, nn0 = m0 & 1023, h = (id >> 5) & 7;
    if (z <= 1) {
#pragma unroll
        for (int mt = 0; mt < 4; mt++)
#pragma unroll
            for (int nt = 0; nt < 2; nt++)
#pragma unroll
                for (int r = 0; r < 4; r++)
                    sh[(wm + mt * 16 + quad * 4 + r) * 72 + wn + nt * 16 + l15] = (f16)acc[mt][nt][r];
        __syncthreads();
        f16* dst = (z == 0) ? Qh : Kf;
        long basebh = ((long)(bb * NH + h)) * NTOK * DH;
#pragma unroll
        for (int q2 = 0; q2 < 4; q2++) {
            int c = tid + q2 * 256;
            int row = c >> 3, col = (c & 7) * 8;
            int n = nn0 + row;
            int nr = (z == 1) ? ((NTOK - n) & (NTOK - 1)) : n;
            *(f16x8*)&dst[basebh + (long)nr * DH + col] = *(const f16x8*)&sh[row * 72 + col];
        }
    } else {
#pragma unroll
        for (int mt = 0; mt < 4; mt++)
#pragma unroll
            for (int nt = 0; nt < 2; nt++)
#pragma unroll
                for (int r = 0; r < 4; r++)
                    sh[(wn + nt * 16 + l15) * 136 + wm + mt * 16 + quad * 4 + r] = (f16)acc[mt][nt][r];
        __syncthreads();
        long basev = ((long)(bb * NH + h)) * DH * NTOK;
#pragma unroll
        for (int q2 = 0; q2 < 4; q2++) {
            int c = tid + q2 * 256;
            int d = c >> 4, col = (c & 15) * 8;
            *(f16x8*)&Vt[basev + (long)d * NTOK + nn0 + col] = *(const f16x8*)&sh[d * 136 + col];
        }
    }
}

// ---- k_attn: kv-SPLIT flash attention, 16q/wave, fp32 partial O + l ---------
// grid 1024: bh = id&31 (XCD cluster), qt = (id>>5)&15, half = id>>9.
__global__ __launch_bounds__(256) void k_attn(const f16* __restrict__ Q, const f16* __restrict__ Kf,
                                              const f16* __restrict__ Vt,
                                              float* __restrict__ Opart, float* __restrict__ lpart) {
    __shared__ __attribute__((aligned(16))) f16 Ksh[128 * 64];
    __shared__ __attribute__((aligned(16))) f16 Vsh[64 * 128];
    __shared__ __attribute__((aligned(16))) f16 PshT[4 * 16 * 136];
    const int id = blockIdx.x, tid = threadIdx.x;
    const int lane = tid & 63, wid = tid >> 6;
    const int quad = lane >> 4, l15 = lane & 15;
    const int bh = id & 31;
    const int rest = id >> 5;
    const int qt = rest & 15, half = rest >> 4;
    const int b = bh >> 3, hh = bh & 7, q0 = qt * 64;
    const int kbase = half * 512;
    const f16* Qbh = Q + (long)bh * NTOK * DH;
    const f16* Kbh = Kf + (long)bh * NTOK * DH;
    const f16* Vbh = Vt + (long)bh * DH * NTOK;
    const int rl = lane >> 3, jj8 = (lane & 7) ^ rl;                 // K swizzle
    const int rl4 = lane >> 4, jjv = (lane & 15) ^ (4 * wid + rl4);  // V swizzle
    const int qrow = q0 + wid * 16 + l15;
    f16x8 qf[2];
    qf[0] = *(const f16x8*)&Qbh[(long)qrow * DH + quad * 8];
    qf[1] = *(const f16x8*)&Qbh[(long)qrow * DH + 32 + quad * 8];
    f32x4 O[4] = {};
    float l_acc = 0.f;                    // partial row-sum for q = l15 (this wave)
    f16* Pw = PshT + wid * 16 * 136;      // wave-local P^T region [q][kv]

    for (int k0 = 0; k0 < 512; k0 += 128) {
        if (k0) __syncthreads();
        const int kb = kbase + k0;
#pragma unroll
        for (int c = 0; c < 4; c++) {
            int rk = c * 32 + 8 * wid + rl;
            glds16(&Kbh[(long)(kb + rk) * DH + 8 * jj8], &Ksh[(c * 32 + 8 * wid) * 64]);
        }
#pragma unroll
        for (int c = 0; c < 4; c++) {
            int rv = c * 16 + 4 * wid + rl4;
            glds16(&Vbh[(long)rv * NTOK + kb + 8 * jjv], &Vsh[(c * 16 + 4 * wid) * 128]);
        }
        __syncthreads();
        // S^T(128kv x 16q) = Kf · Q^T : lane holds S[q=l15][kv=16nt+quad*4+r]
        f32x4 st[8] = {};
#pragma unroll
        for (int ks = 0; ks < 2; ks++) {
            const int slot = ((ks * 4 + quad) ^ (l15 & 7)) * 8;
#pragma unroll
            for (int nt = 0; nt < 8; nt++) {
                f16x8 kf = *(const f16x8*)&Ksh[(nt * 16 + l15) * 64 + slot];
                st[nt] = __builtin_amdgcn_mfma_f32_16x16x32_f16(kf, qf[ks], st[nt], 0, 0, 0);
            }
        }
        // P = exp(|S|-8) (shift-invariant; |S|max~9.4 << 19); packed b64 writes
#pragma unroll
        for (int nt = 0; nt < 8; nt++) {
            float p0 = __expf(fminf(fabsf(st[nt][0]) - 8.f, 11.f));
            float p1 = __expf(fminf(fabsf(st[nt][1]) - 8.f, 11.f));
            float p2 = __expf(fminf(fabsf(st[nt][2]) - 8.f, 11.f));
            float p3 = __expf(fminf(fabsf(st[nt][3]) - 8.f, 11.f));
            l_acc += (p0 + p1) + (p2 + p3);
            f16x4 pk = { (f16)p0, (f16)p1, (f16)p2, (f16)p3 };
            *(f16x4*)&Pw[l15 * 136 + 16 * nt + quad * 4] = pk;   // wave-local, no barrier
        }
        // O(16q x 64d) += P @ V
#pragma unroll
        for (int ks = 0; ks < 4; ks++) {
            f16x8 pf = *(const f16x8*)&Pw[l15 * 136 + 32 * ks + quad * 8];
            const int vslot = ((ks * 4 + quad) ^ l15) * 8;
#pragma unroll
            for (int vt = 0; vt < 4; vt++) {
                f16x8 vf = *(const f16x8*)&Vsh[(vt * 16 + l15) * 128 + vslot];
                O[vt] = __builtin_amdgcn_mfma_f32_16x16x32_f16(pf, vf, O[vt], 0, 0, 0);
            }
        }
    }
    // l partial: sum quads; quad 0 stores (coalesced)
    l_acc += __shfl_xor(l_acc, 16, 64);
    l_acc += __shfl_xor(l_acc, 32, 64);
    if (quad == 0) lpart[half * (32 * NTOK) + bh * NTOK + qrow] = l_acc;
    // O partial: fp32 unnormalized
    float* Od = Opart + (size_t)half * ROWS * 512;
#pragma unroll
    for (int t = 0; t < 4; t++)
#pragma unroll
        for (int r = 0; r < 4; r++) {
            int gn = q0 + wid * 16 + quad * 4 + r;
            int gc = hh * DH + t * 16 + l15;
            Od[((long)b * NTOK + gn) * 512 + gc] = O[t][r];
        }
}

// ---- k_comb: combine kv-halves + spread batch stats (0..2047) | film2 -------
__global__ __launch_bounds__(256) void k_comb(const float* __restrict__ Opart, const float* __restrict__ lpart,
                                              f16* __restrict__ aout16, float* __restrict__ statsp,
                                              const float* __restrict__ tbacc, const float* __restrict__ w_emd2,
                                              float* __restrict__ filmp) {
    __shared__ float tsh[128];
    __shared__ float rbuf[8];
    const int id = blockIdx.x, tid = threadIdx.x;
    if (id >= 2048) {
        // FiLM layer 2 split-K: filmp[b][c] += silu(tbacc[b][k])·w2[k][c]
        int pid = id - 2048;
        int c = (pid & 3) * 256 + tid;
        int k0 = (pid >> 2) * 32;                  // 32 K-splits
        if (tid < 128) {
            float v = tbacc[(tid >> 5) * 1024 + k0 + (tid & 31)];
            tsh[(tid >> 5) * 32 + (tid & 31)] = v / (1.f + __expf(-v));   // silu
        }
        __syncthreads();
        float a0 = 0.f, a1 = 0.f, a2 = 0.f, a3 = 0.f;
#pragma unroll 8
        for (int k = 0; k < 32; k++) {
            float w = w_emd2[(k0 + k) * 1024 + c];
            a0 += tsh[k] * w; a1 += tsh[32 + k] * w; a2 += tsh[64 + k] * w; a3 += tsh[96 + k] * w;
        }
        atomicAdd(&filmp[c], a0);        atomicAdd(&filmp[1024 + c], a1);
        atomicAdd(&filmp[2048 + c], a2); atomicAdd(&filmp[3072 + c], a3);
        return;
    }
    const int lane = tid & 63, wid = tid >> 6;
    long base = ((long)id * 256 + tid) * 4;
    int b = (int)(base >> 19);
    int row = (int)(base >> 9);                    // b*1024 + n
    int n = row & 1023;
    int col = (int)(base & 511);
    int h = col >> 6;
    int bhn = (b * 8 + h) * NTOK + n;
    float4 o0 = *(const float4*)&Opart[base];
    float4 o1 = *(const float4*)&Opart[(size_t)ROWS * 512 + base];
    float fr = 0.125f / (lpart[bhn] + lpart[32 * NTOK + bhn]);
    float v0 = (o0.x + o1.x) * fr, v1 = (o0.y + o1.y) * fr;
    float v2 = (o0.z + o1.z) * fr, v3 = (o0.w + o1.w) * fr;
    f16x4 pk = { (f16)v0, (f16)v1, (f16)v2, (f16)v3 };
    *(f16x4*)&aout16[base] = pk;
    float lsum = (v0 + v1) + (v2 + v3);
    float lsq = (v0 * v0 + v1 * v1) + (v2 * v2 + v3 * v3);
#pragma unroll
    for (int d = 32; d >= 1; d >>= 1) { lsum += __shfl_xor(lsum, d, 64); lsq += __shfl_xor(lsq, d, 64); }
    if (lane == 0) { rbuf[wid] = lsum; rbuf[4 + wid] = lsq; }
    __syncthreads();
    if (tid == 0) {
        // spread over 64 slots x 64B: ~64 atomics/line instead of 4096/line
        float* sp = statsp + (id & 63) * 16;
        atomicAdd(&sp[b * 2], rbuf[0] + rbuf[1] + rbuf[2] + rbuf[3]);
        atomicAdd(&sp[b * 2 + 1], rbuf[4] + rbuf[5] + rbuf[6] + rbuf[7]);
    }
}

// ---- gemm2 + fused global-norm/FiLM on A; emits fp16 out1 + row stats -------
__global__ __launch_bounds__(256) void k_gemm2f(const f16* __restrict__ aout16, const float* __restrict__ statsp,
                                                const float* __restrict__ filmp,
                                                const f16* __restrict__ BT, const float* __restrict__ bias,
                                                f16* __restrict__ out1h, float* __restrict__ rstats) {
    __shared__ __attribute__((aligned(16))) f16 Ash[64 * 128];
    __shared__ __attribute__((aligned(16))) f16 Bsh[64 * 128];
    __shared__ float scsh[512], shsh[512];
    __shared__ float sred[2];
    const int tid = threadIdx.x;
    const int lane = tid & 63, wid = tid >> 6;
    const int quad = lane >> 4, l15 = lane & 15;
    const int m0 = blockIdx.x * 64, n0 = blockIdx.y * 64;
    const int wm = (wid >> 1) * 32, wn = (wid & 1) * 32;
    const int srow = lane >> 4, slot = lane & 15;
    const int b = m0 >> 10;
    if (tid < 64) {   // reduce the 64 spread stats slots (wave 0)
        float s = statsp[tid * 16 + b * 2];
        float q = statsp[tid * 16 + b * 2 + 1];
#pragma unroll
        for (int d = 32; d >= 1; d >>= 1) { s += __shfl_xor(s, d, 64); q += __shfl_xor(q, d, 64); }
        if (tid == 0) { sred[0] = s; sred[1] = q; }
    }
    __syncthreads();
    {   // per-column scale/shift table (batch-wide stats)
        float sum = sred[0], sq = sred[1];
        const float M = 524288.f;
        float mu = sum / M;
        float isd = rsqrtf((sq - sum * mu) / (M - 1.f));   // torch.std ddof=1
        for (int c = tid; c < 512; c += 256) {
            float sc = isd * filmp[b * 1024 + 512 + c];
            scsh[c] = sc;
            shsh[c] = filmp[b * 1024 + c] - mu * sc;
        }
    }
    __syncthreads();
    f32x4 acc[2][2] = {};
    for (int kk = 0; kk < 512; kk += 128) {
        if (kk) __syncthreads();
        const int j = slot ^ ((4 * wid + srow) & 7);   // constant per thread
        const int gcol = kk + 8 * j;
        float sc[8], sf[8];
        *(float4*)&sc[0] = *(const float4*)&scsh[gcol];
        *(float4*)&sc[4] = *(const float4*)&scsh[gcol + 4];
        *(float4*)&sf[0] = *(const float4*)&shsh[gcol];
        *(float4*)&sf[4] = *(const float4*)&shsh[gcol + 4];
#pragma unroll
        for (int c = 0; c < 4; c++) {
            int r = c * 16 + 4 * wid + srow;
            f16x8 v = *(const f16x8*)&aout16[(long)(m0 + r) * 512 + gcol];
            f16x8 y;
#pragma unroll
            for (int e = 0; e < 8; e++) y[e] = (f16)((float)v[e] * sc[e] + sf[e]);
            *(f16x8*)&Ash[(c * 16 + 4 * wid) * 128 + lane * 8] = y;
            glds16(&BT[(long)(n0 + r) * 512 + kk + 8 * j], &Bsh[(c * 16 + 4 * wid) * 128]);
        }
        __syncthreads();
#pragma unroll
        for (int ks = 0; ks < 4; ks++) {
            const int rslot = ((ks * 4 + quad) ^ (l15 & 7)) * 8;
            f16x8 af[2], bf[2];
#pragma unroll
            for (int t = 0; t < 2; t++) {
                af[t] = *(const f16x8*)&Ash[(wm + t * 16 + l15) * 128 + rslot];
                bf[t] = *(const f16x8*)&Bsh[(wn + t * 16 + l15) * 128 + rslot];
            }
#pragma unroll
            for (int mt = 0; mt < 2; mt++)
#pragma unroll
                for (int nt = 0; nt < 2; nt++)
                    acc[mt][nt] = __builtin_amdgcn_mfma_f32_16x16x32_f16(af[mt], bf[nt], acc[mt][nt], 0, 0, 0);
        }
    }
    // epilogue: +bias, fp16 store, per-row sum/sumsq partials -> rstats
#pragma unroll
    for (int mt = 0; mt < 2; mt++)
#pragma unroll
        for (int r = 0; r < 4; r++) {
            int gm = m0 + wm + mt * 16 + quad * 4 + r;
            float v0 = acc[mt][0][r] + bias[n0 + wn + l15];
            float v1 = acc[mt][1][r] + bias[n0 + wn + 16 + l15];
            out1h[(long)gm * 512 + n0 + wn + l15] = (f16)v0;
            out1h[(long)gm * 512 + n0 + wn + 16 + l15] = (f16)v1;
            float s = v0 + v1, q2 = v0 * v0 + v1 * v1;
#pragma unroll
            for (int d = 8; d >= 1; d >>= 1) { s += __shfl_xor(s, d, 16); q2 += __shfl_xor(q2, d, 16); }
            if (l15 == 0) {
                atomicAdd(&rstats[gm * 2], s);
                atomicAdd(&rstats[gm * 2 + 1], q2);
            }
        }
}

// ---- gemm3 with fused LayerNorm on A (row mu/inv + col g/b), GELU out -------
__global__ __launch_bounds__(256) void k_gemm3f(const f16* __restrict__ out1h, const float* __restrict__ rstats,
                                                const float* __restrict__ lng, const float* __restrict__ lnb,
                                                const f16* __restrict__ BT, const float* __restrict__ bias,
                                                f16* __restrict__ X4) {
    __shared__ __attribute__((aligned(16))) f16 Ash[64 * 128];
    __shared__ __attribute__((aligned(16))) f16 Bsh[64 * 128];
    __shared__ float musr[64], invsr[64], gsh[512], bsh[512];
    const int tid = threadIdx.x;
    const int lane = tid & 63, wid = tid >> 6;
    const int quad = lane >> 4, l15 = lane & 15;
    const int m0 = blockIdx.x * 64, n0 = blockIdx.y * 64;
    const int wm = (wid >> 1) * 32, wn = (wid & 1) * 32;
    const int srow = lane >> 4, slot = lane & 15;
    if (tid < 64) {
        float s = rstats[(m0 + tid) * 2], sq = rstats[(m0 + tid) * 2 + 1];
        float mu = s * (1.f / 512.f);
        float var = sq * (1.f / 512.f) - mu * mu;
        musr[tid] = mu;
        invsr[tid] = rsqrtf(var + 1e-5f);
    }
    for (int i = tid; i < 512; i += 256) { gsh[i] = lng[i]; bsh[i] = lnb[i]; }
    __syncthreads();
    f32x4 acc[2][2] = {};
    for (int kk = 0; kk < 512; kk += 128) {
        if (kk) __syncthreads();
        const int j = slot ^ ((4 * wid + srow) & 7);   // constant per thread
        const int gcol = kk + 8 * j;
        float gv[8], bv[8];
        *(float4*)&gv[0] = *(const float4*)&gsh[gcol];
        *(float4*)&gv[4] = *(const float4*)&gsh[gcol + 4];
        *(float4*)&bv[0] = *(const float4*)&bsh[gcol];
        *(float4*)&bv[4] = *(const float4*)&bsh[gcol + 4];
#pragma unroll
        for (int c = 0; c < 4; c++) {
            int r = c * 16 + 4 * wid + srow;
            f16x8 x = *(const f16x8*)&out1h[(long)(m0 + r) * 512 + gcol];
            float a = invsr[r], m = musr[r];
            f16x8 y;
#pragma unroll
            for (int e = 0; e < 8; e++) {
                float sc = a * gv[e];
                y[e] = (f16)((float)x[e] * sc + (bv[e] - m * sc));
            }
            *(f16x8*)&Ash[(c * 16 + 4 * wid) * 128 + lane * 8] = y;
            glds16(&BT[(long)(n0 + r) * 512 + kk + 8 * j], &Bsh[(c * 16 + 4 * wid) * 128]);
        }
        __syncthreads();
#pragma unroll
        for (int ks = 0; ks < 4; ks++) {
            const int rslot = ((ks * 4 + quad) ^ (l15 & 7)) * 8;
            f16x8 af[2], bf[2];
#pragma unroll
            for (int t = 0; t < 2; t++) {
                af[t] = *(const f16x8*)&Ash[(wm + t * 16 + l15) * 128 + rslot];
                bf[t] = *(const f16x8*)&Bsh[(wn + t * 16 + l15) * 128 + rslot];
            }
#pragma unroll
            for (int mt = 0; mt < 2; mt++)
#pragma unroll
                for (int nt = 0; nt < 2; nt++)
                    acc[mt][nt] = __builtin_amdgcn_mfma_f32_16x16x32_f16(af[mt], bf[nt], acc[mt][nt], 0, 0, 0);
        }
    }
#pragma unroll
    for (int mt = 0; mt < 2; mt++)
#pragma unroll
        for (int nt = 0; nt < 2; nt++)
#pragma unroll
            for (int r = 0; r < 4; r++) {
                int gm = m0 + wm + mt * 16 + quad * 4 + r;
                int gn = n0 + wn + nt * 16 + l15;
                float x = acc[mt][nt][r] + bias[gn];
                X4[(long)gm * 512 + gn] = (f16)(0.5f * x * (1.0f + erff(x * 0.70710678f)));
            }
}

// ---- 64x64-tile GEMM, BK=128, glds+swizzle (final: +bias fp32) --------------
__global__ __launch_bounds__(256) void k_gemm4(const f16* __restrict__ A, const f16* __restrict__ BT,
                                               const float* __restrict__ bias, float* __restrict__ dst) {
    __shared__ __attribute__((aligned(16))) f16 Ash[64 * 128];
    __shared__ __attribute__((aligned(16))) f16 Bsh[64 * 128];
    const int tid = threadIdx.x;
    const int lane = tid & 63, wid = tid >> 6;
    const int quad = lane >> 4, l15 = lane & 15;
    const int m0 = blockIdx.x * 64, n0 = blockIdx.y * 64;
    const int wm = (wid >> 1) * 32, wn = (wid & 1) * 32;
    const int srow = lane >> 4, slot = lane & 15;
    f32x4 acc[2][2] = {};
    for (int kk = 0; kk < 512; kk += 128) {
        if (kk) __syncthreads();
#pragma unroll
        for (int c = 0; c < 4; c++) {
            int r = c * 16 + 4 * wid + srow;
            int j = slot ^ (r & 7);
            glds16(&A[(long)(m0 + r) * 512 + kk + 8 * j], &Ash[(c * 16 + 4 * wid) * 128]);
            glds16(&BT[(long)(n0 + r) * 512 + kk + 8 * j], &Bsh[(c * 16 + 4 * wid) * 128]);
        }
        __syncthreads();
#pragma unroll
        for (int ks = 0; ks < 4; ks++) {
            const int rslot = ((ks * 4 + quad) ^ (l15 & 7)) * 8;
            f16x8 af[2], bf[2];
#pragma unroll
            for (int t = 0; t < 2; t++) {
                af[t] = *(const f16x8*)&Ash[(wm + t * 16 + l15) * 128 + rslot];
                bf[t] = *(const f16x8*)&Bsh[(wn + t * 16 + l15) * 128 + rslot];
            }
#pragma unroll
            for (int mt = 0; mt < 2; mt++)
#pragma unroll
                for (int nt = 0; nt < 2; nt++)
                    acc[mt][nt] = __builtin_amdgcn_mfma_f32_16x16x32_f16(af[mt], bf[nt], acc[mt][nt], 0, 0, 0);
        }
    }
#pragma unroll
    for (int mt = 0; mt < 2; mt++)
#pragma unroll
        for (int nt = 0; nt < 2; nt++)
#pragma unroll
            for (int r = 0; r < 4; r++) {
                int gm = m0 + wm + mt * 16 + quad * 4 + r;
                int gn = n0 + wn + nt * 16 + l15;
                dst[(long)gm * 512 + gn] = acc[mt][nt][r] + bias[gn];
            }
}

// ----------------------------------------------------------------------------
extern "C" void kernel_launch(void* const* d_in, const int* in_sizes, int n_in,
                              void* d_out, int out_size, void* d_ws, size_t ws_size,
                              hipStream_t stream) {
    const float* con      = (const float*)d_in[0];
    const float* diff     = (const float*)d_in[1];
    const float* temb     = (const float*)d_in[2];
    const float* ln_con_g = (const float*)d_in[3];
    const float* ln_con_b = (const float*)d_in[4];
    const float* ln_dif_g = (const float*)d_in[5];
    const float* ln_dif_b = (const float*)d_in[6];
    const float* wq       = (const float*)d_in[7];
    const float* wk       = (const float*)d_in[8];
    const float* wv       = (const float*)d_in[9];
    const float* w_out    = (const float*)d_in[10];
    const float* b_out    = (const float*)d_in[11];
    const float* w_emd1   = (const float*)d_in[12];
    const float* b_emd1   = (const float*)d_in[13];
    const float* w_emd2   = (const float*)d_in[14];
    const float* b_emd2   = (const float*)d_in[15];
    const float* mlp_ln_g = (const float*)d_in[16];
    const float* mlp_ln_b = (const float*)d_in[17];
    const float* mlp_w1   = (const float*)d_in[18];
    const float* mlp_b1   = (const float*)d_in[19];
    const float* mlp_w2   = (const float*)d_in[20];
    const float* mlp_b2   = (const float*)d_in[21];
    float* outp = (float*)d_out;

    char* ws = (char*)d_ws;
    size_t off = 0;
    auto alloc = [&](size_t bytes) { void* p = ws + off; off += (bytes + 255) & ~(size_t)255; return p; };
    f16*   A16   = (f16*)alloc((size_t)ROWS * 512 * 2);   // LN(diff)
    f16*   C16   = (f16*)alloc((size_t)ROWS * 512 * 2);   // LN(con); later X4
    f16*   Qh    = (f16*)alloc((size_t)ROWS * 512 * 2);   // later out1h
    f16*   Kf    = (f16*)alloc((size_t)ROWS * 512 * 2);
    f16*   Vt    = (f16*)alloc((size_t)ROWS * 512 * 2);
    f16*   aout16= (f16*)alloc((size_t)ROWS * 512 * 2);   // combined attn out, fp16
    float* Opart = (float*)alloc((size_t)2 * ROWS * 512 * 4);   // kv-split partials
    float* lpart = (float*)alloc((size_t)2 * 32 * NTOK * 4);
    f16*   wqT   = (f16*)alloc(512 * 512 * 2);
    f16*   wkT   = (f16*)alloc(512 * 512 * 2);
    f16*   wvT   = (f16*)alloc(512 * 512 * 2);
    f16*   woT   = (f16*)alloc(512 * 512 * 2);
    f16*   w1T   = (f16*)alloc(512 * 512 * 2);
    f16*   w2T   = (f16*)alloc(512 * 512 * 2);
    float* tbacc = (float*)alloc(4 * 1024 * 4);
    float* filmp = (float*)alloc(4 * 1024 * 4);
    float* statsp= (float*)alloc(64 * 16 * 4);            // 64 spread slots x 64B
    float* rstats= (float*)alloc(ROWS * 2 * 4);
    f16*   out1h = Qh;    // overlay (Qh dead after attn)
    f16*   X4    = C16;   // overlay (C16 dead after qkv)

    PrepArgs pa;
    pa.src[0] = wq;  pa.src[1] = wk;  pa.src[2] = wv;
    pa.src[3] = w_out; pa.src[4] = mlp_w1; pa.src[5] = mlp_w2;
    pa.dst[0] = wqT; pa.dst[1] = wkT; pa.dst[2] = wvT;
    pa.dst[3] = woT; pa.dst[4] = w1T; pa.dst[5] = w2T;

    k_pre<<<dim3(3632), dim3(256), 0, stream>>>(pa, statsp, b_emd1, b_emd2, tbacc, filmp, rstats,
                                                diff, ln_dif_g, ln_dif_b, A16,
                                                con, ln_con_g, ln_con_b, C16);
    k_qkv<<<dim3(832), dim3(256), 0, stream>>>(A16, C16, wqT, wkT, wvT, Qh, Kf, Vt,
                                               temb, w_emd1, tbacc);
    k_attn<<<dim3(1024), dim3(256), 0, stream>>>(Qh, Kf, Vt, Opart, lpart);
    k_comb<<<dim3(2176), dim3(256), 0, stream>>>(Opart, lpart, aout16, statsp,
                                                 tbacc, w_emd2, filmp);
    k_gemm2f<<<dim3(64, 8), dim3(256), 0, stream>>>(aout16, statsp, filmp, woT, b_out, out1h, rstats);
    k_gemm3f<<<dim3(64, 8), dim3(256), 0, stream>>>(out1h, rstats, mlp_ln_g, mlp_ln_b, w1T, mlp_b1, X4);
    k_gemm4<<<dim3(64, 8), dim3(256), 0, stream>>>(X4, w2T, mlp_b2, outp);
}

// Round 12
// 177.884 us; speedup vs baseline: 1.3199x; 1.0226x over previous
//
#include <hip/hip_runtime.h>
#include <math.h>

// ----------------------------------------------------------------------------
// Cross_Attention_Fourier collapses analytically:
//   fft2/ifft2 (ortho) around QK^T reduce to:  attn_c[q,l] = Q[q]·K[(N-l)%N]
//   => softmax(|Q·Kflip^T|) attention with V UNflipped (flip folded into K).
// R12: consolidation — R8's single-pass attn (no Opart round-trip, film2
//     rides attn, 6 launches) + R11's spread-slot stats (64 padded lines;
//     single-line device atomics cost ~14ns each serialized — R10 lesson).
//     gemm2f shuffle-reduces the 64 partial slots.
// ----------------------------------------------------------------------------

typedef _Float16 f16;
typedef _Float16 f16x4 __attribute__((ext_vector_type(4)));
typedef _Float16 f16x8 __attribute__((ext_vector_type(8)));
typedef float f32x4 __attribute__((ext_vector_type(4)));

#define ROWS 4096   // B*N = 4*1024
#define NTOK 1024
#define NB   4
#define NH   8
#define DH   64

__device__ __forceinline__ void glds16(const f16* g, f16* l) {
    __builtin_amdgcn_global_load_lds((const __attribute__((address_space(1))) void*)g,
                                     (__attribute__((address_space(3))) void*)l, 16, 0, 0);
}

struct PrepArgs { const float* src[6]; f16* dst[6]; };

// ---- LN helper: one wave, one 512-row --------------------------------------
__device__ __forceinline__ void ln_row(const float* __restrict__ x, const float* __restrict__ g,
                                       const float* __restrict__ bb, f16* __restrict__ o, int lane) {
    float v[8]; float s = 0.f;
#pragma unroll
    for (int j = 0; j < 8; j++) { v[j] = x[lane + 64 * j]; s += v[j]; }
#pragma unroll
    for (int d = 32; d >= 1; d >>= 1) s += __shfl_xor(s, d, 64);
    float mean = s * (1.f / 512.f);
    float q = 0.f;
#pragma unroll
    for (int j = 0; j < 8; j++) { float t = v[j] - mean; q += t * t; }
#pragma unroll
    for (int d = 32; d >= 1; d >>= 1) q += __shfl_xor(q, d, 64);
    float inv = rsqrtf(q * (1.f / 512.f) + 1e-5f);
#pragma unroll
    for (int j = 0; j < 8; j++) {
        int c = lane + 64 * j;
        o[c] = (f16)((v[j] - mean) * inv * g[c] + bb[c]);
    }
}

// ---- k_pre: init (0..47) | weight prep (48..1583) | LN (1584..3631) ---------
__global__ __launch_bounds__(256) void k_pre(PrepArgs pa, float* statsp,
                                             const float* __restrict__ b_emd1, const float* __restrict__ b_emd2,
                                             float* __restrict__ tbacc, float* __restrict__ filmp,
                                             float* __restrict__ rstats,
                                             const float* __restrict__ diff, const float* __restrict__ g_dif,
                                             const float* __restrict__ b_dif, f16* __restrict__ A16,
                                             const float* __restrict__ con, const float* __restrict__ g_con,
                                             const float* __restrict__ b_con, f16* __restrict__ C16) {
    __shared__ float smem[1056];
    const int id = blockIdx.x, tid = threadIdx.x;
    if (id < 16) {
        int o = id * 256 + tid;                    // [0,4096)
        tbacc[o] = b_emd1[o & 1023];
        filmp[o] = b_emd2[o & 1023];
        if (id < 4) statsp[id * 256 + tid] = 0.f;  // 64 slots x 16 floats
    } else if (id < 48) {
        rstats[(id - 16) * 256 + tid] = 0.f;       // 8192 floats
    } else if (id < 1584) {
        int pid = id - 48;
        int m = pid >> 8, rem = pid & 255;
        int o0 = (rem & 15) * 32, i0 = (rem >> 4) * 32;
        int tx = tid & 31, ty = tid >> 5;
        const float* src = pa.src[m];
        f16* dst = pa.dst[m];
        for (int r = ty; r < 32; r += 8)
            smem[r * 33 + tx] = src[(i0 + r) * 512 + o0 + tx];
        __syncthreads();
        for (int r = ty; r < 32; r += 8)
            dst[(o0 + r) * 512 + i0 + tx] = (f16)smem[tx * 33 + r];
    } else {
        int lane = tid & 63, wid = tid >> 6;
        long row = (long)(id - 1584) * 4 + wid;
        if (row < ROWS) ln_row(diff + row * 512, g_dif, b_dif, A16 + row * 512, lane);
        else { long r = row - ROWS; ln_row(con + r * 512, g_con, b_con, C16 + r * 512, lane); }
    }
}

// ---- k_qkv: qkv (0..767) | film1 split-K (768..831) -------------------------
// z=0: Qh[b][h][n][d]; z=1: Kf[b][h][flip(n)][d]; z=2: Vt[b][h][d][n]
__global__ __launch_bounds__(256) void k_qkv(const f16* __restrict__ A16, const f16* __restrict__ C16,
                                             const f16* __restrict__ wqT, const f16* __restrict__ wkT,
                                             const f16* __restrict__ wvT,
                                             f16* __restrict__ Qh, f16* __restrict__ Kf, f16* __restrict__ Vt,
                                             const float* __restrict__ temb, const float* __restrict__ w_emd1,
                                             float* __restrict__ tbacc) {
    __shared__ __attribute__((aligned(16))) f16 sh[128 * 128 + 64 * 128];   // 48 KB
    const int id = blockIdx.x, tid = threadIdx.x;
    if (id >= 768) {
        float* tsh = (float*)sh;   // [4][32]
        int pid = id - 768;
        int c = (pid & 3) * 256 + tid;
        int k0 = (pid >> 2) * 32;                  // 16 K-splits
        if (tid < 128) tsh[(tid >> 5) * 32 + (tid & 31)] = temb[(tid >> 5) * 512 + k0 + (tid & 31)];
        __syncthreads();
        float a0 = 0.f, a1 = 0.f, a2 = 0.f, a3 = 0.f;
#pragma unroll 8
        for (int k = 0; k < 32; k++) {
            float w = w_emd1[(k0 + k) * 1024 + c];
            a0 += tsh[k] * w; a1 += tsh[32 + k] * w; a2 += tsh[64 + k] * w; a3 += tsh[96 + k] * w;
        }
        atomicAdd(&tbacc[c], a0);        atomicAdd(&tbacc[1024 + c], a1);
        atomicAdd(&tbacc[2048 + c], a2); atomicAdd(&tbacc[3072 + c], a3);
        return;
    }
    f16* Ash = sh;
    f16* Bsh = sh + 128 * 128;
    const int z = id >> 8;
    const f16* A  = (z == 0) ? A16 : C16;
    const f16* BT = (z == 0) ? wqT : (z == 1) ? wkT : wvT;
    const int lane = tid & 63, wid = tid >> 6;
    const int quad = lane >> 4, l15 = lane & 15;
    const int m0 = (id & 31) * 128, n0 = ((id >> 5) & 7) * 64;
    const int wm = (wid >> 1) * 64, wn = (wid & 1) * 32;
    const int srow = lane >> 4, slot = lane & 15;
    f32x4 acc[4][2] = {};
    for (int kk = 0; kk < 512; kk += 128) {
        if (kk) __syncthreads();
#pragma unroll
        for (int c = 0; c < 8; c++) {
            int r = c * 16 + 4 * wid + srow;
            int j = slot ^ (r & 7);
            glds16(&A[(long)(m0 + r) * 512 + kk + 8 * j], &Ash[(c * 16 + 4 * wid) * 128]);
        }
#pragma unroll
        for (int c = 0; c < 4; c++) {
            int r = c * 16 + 4 * wid + srow;
            int j = slot ^ (r & 7);
            glds16(&BT[(long)(n0 + r) * 512 + kk + 8 * j], &Bsh[(c * 16 + 4 * wid) * 128]);
        }
        __syncthreads();
#pragma unroll
        for (int ks = 0; ks < 4; ks++) {
            const int rslot = ((ks * 4 + quad) ^ (l15 & 7)) * 8;
            f16x8 af[4], bf[2];
#pragma unroll
            for (int t = 0; t < 4; t++)
                af[t] = *(const f16x8*)&Ash[(wm + t * 16 + l15) * 128 + rslot];
#pragma unroll
            for (int t = 0; t < 2; t++)
                bf[t] = *(const f16x8*)&Bsh[(wn + t * 16 + l15) * 128 + rslot];
#pragma unroll
            for (int mt = 0; mt < 4; mt++)
#pragma unroll
                for (int nt = 0; nt < 2; nt++)
                    acc[mt][nt] = __builtin_amdgcn_mfma_f32_16x16x32_f16(af[mt], bf[nt], acc[mt][nt], 0, 0, 0);
        }
    }
    __syncthreads();
    const int bb = m0 >> 10, nn0 = m0 & 1023, h = (id >> 5) & 7;
    if (z <= 1) {
#pragma unroll
        for (int mt = 0; mt < 4; mt++)
#pragma unroll
            for (int nt = 0; nt < 2; nt++)
#pragma unroll
                for (int r = 0; r < 4; r++)
                    sh[(wm + mt * 16 + quad * 4 + r) * 72 + wn + nt * 16 + l15] = (f16)acc[mt][nt][r];
        __syncthreads();
        f16* dst = (z == 0) ? Qh : Kf;
        long basebh = ((long)(bb * NH + h)) * NTOK * DH;
#pragma unroll
        for (int q2 = 0; q2 < 4; q2++) {
            int c = tid + q2 * 256;
            int row = c >> 3, col = (c & 7) * 8;
            int n = nn0 + row;
            int nr = (z == 1) ? ((NTOK - n) & (NTOK - 1)) : n;
            *(f16x8*)&dst[basebh + (long)nr * DH + col] = *(const f16x8*)&sh[row * 72 + col];
        }
    } else {
#pragma unroll
        for (int mt = 0; mt < 4; mt++)
#pragma unroll
            for (int nt = 0; nt < 2; nt++)
#pragma unroll
                for (int r = 0; r < 4; r++)
                    sh[(wn + nt * 16 + l15) * 136 + wm + mt * 16 + quad * 4 + r] = (f16)acc[mt][nt][r];
        __syncthreads();
        long basev = ((long)(bb * NH + h)) * DH * NTOK;
#pragma unroll
        for (int q2 = 0; q2 < 4; q2++) {
            int c = tid + q2 * 256;
            int d = c >> 4, col = (c & 15) * 8;
            *(f16x8*)&Vt[basev + (long)d * NTOK + nn0 + col] = *(const f16x8*)&sh[d * 136 + col];
        }
    }
}

// ---- k_attn: single-pass attn 16q/wave (0..511) | film2 split-K (512..639) --
// S^T = Kf·Q^T (lane holds 4 consecutive kv of one q-col -> b64 P-writes);
// P = exp(|S|-8) (shift-invariant); l in registers; fp16 out; SPREAD stats.
__global__ __launch_bounds__(256) void k_attn(const f16* __restrict__ Q, const f16* __restrict__ Kf,
                                              const f16* __restrict__ Vt, f16* __restrict__ out,
                                              float* __restrict__ statsp,
                                              const float* __restrict__ tbacc, const float* __restrict__ w_emd2,
                                              float* __restrict__ filmp) {
    __shared__ __attribute__((aligned(16))) f16 Ksh[128 * 64];
    __shared__ __attribute__((aligned(16))) f16 Vsh[64 * 128];
    __shared__ __attribute__((aligned(16))) f16 PshT[4 * 16 * 136];
    __shared__ float rbuf[8];
    const int id = blockIdx.x, tid = threadIdx.x;
    if (id >= 512) {
        float* tsh = (float*)Ksh;   // [4][32]
        int pid = id - 512;
        int c = (pid & 3) * 256 + tid;
        int k0 = (pid >> 2) * 32;                  // 32 K-splits
        if (tid < 128) {
            float v = tbacc[(tid >> 5) * 1024 + k0 + (tid & 31)];
            tsh[(tid >> 5) * 32 + (tid & 31)] = v / (1.f + __expf(-v));   // silu
        }
        __syncthreads();
        float a0 = 0.f, a1 = 0.f, a2 = 0.f, a3 = 0.f;
#pragma unroll 8
        for (int k = 0; k < 32; k++) {
            float w = w_emd2[(k0 + k) * 1024 + c];
            a0 += tsh[k] * w; a1 += tsh[32 + k] * w; a2 += tsh[64 + k] * w; a3 += tsh[96 + k] * w;
        }
        atomicAdd(&filmp[c], a0);        atomicAdd(&filmp[1024 + c], a1);
        atomicAdd(&filmp[2048 + c], a2); atomicAdd(&filmp[3072 + c], a3);
        return;
    }
    const int lane = tid & 63, wid = tid >> 6;
    const int quad = lane >> 4, l15 = lane & 15;
    const int bh = id & 31;                        // same-bh blocks stride 32 -> same XCD
    const int b = bh >> 3, hh = bh & 7, q0 = (id >> 5) * 64;
    const f16* Qbh = Q + (long)bh * NTOK * DH;
    const f16* Kbh = Kf + (long)bh * NTOK * DH;
    const f16* Vbh = Vt + (long)bh * DH * NTOK;
    const int rl = lane >> 3, jj8 = (lane & 7) ^ rl;                 // K swizzle
    const int rl4 = lane >> 4, jjv = (lane & 15) ^ (4 * wid + rl4);  // V swizzle
    const int qrow = q0 + wid * 16 + l15;
    f16x8 qf[2];
    qf[0] = *(const f16x8*)&Qbh[(long)qrow * DH + quad * 8];
    qf[1] = *(const f16x8*)&Qbh[(long)qrow * DH + 32 + quad * 8];
    f32x4 O[4] = {};
    float l_acc = 0.f;                    // partial row-sum for q = l15 (this wave)
    f16* Pw = PshT + wid * 16 * 136;      // wave-local P^T region [q][kv]

    for (int k0 = 0; k0 < NTOK; k0 += 128) {
        if (k0) __syncthreads();
#pragma unroll
        for (int c = 0; c < 4; c++) {
            int rk = c * 32 + 8 * wid + rl;
            glds16(&Kbh[(long)(k0 + rk) * DH + 8 * jj8], &Ksh[(c * 32 + 8 * wid) * 64]);
        }
#pragma unroll
        for (int c = 0; c < 4; c++) {
            int rv = c * 16 + 4 * wid + rl4;
            glds16(&Vbh[(long)rv * NTOK + k0 + 8 * jjv], &Vsh[(c * 16 + 4 * wid) * 128]);
        }
        __syncthreads();
        // S^T(128kv x 16q) = Kf · Q^T : lane holds S[q=l15][kv=16nt+quad*4+r]
        f32x4 st[8] = {};
#pragma unroll
        for (int ks = 0; ks < 2; ks++) {
            const int slot = ((ks * 4 + quad) ^ (l15 & 7)) * 8;
#pragma unroll
            for (int nt = 0; nt < 8; nt++) {
                f16x8 kf = *(const f16x8*)&Ksh[(nt * 16 + l15) * 64 + slot];
                st[nt] = __builtin_amdgcn_mfma_f32_16x16x32_f16(kf, qf[ks], st[nt], 0, 0, 0);
            }
        }
        // P = exp(|S|-8) (shift-invariant; |S|max~9.4 << 19); packed b64 writes
#pragma unroll
        for (int nt = 0; nt < 8; nt++) {
            float p0 = __expf(fminf(fabsf(st[nt][0]) - 8.f, 11.f));
            float p1 = __expf(fminf(fabsf(st[nt][1]) - 8.f, 11.f));
            float p2 = __expf(fminf(fabsf(st[nt][2]) - 8.f, 11.f));
            float p3 = __expf(fminf(fabsf(st[nt][3]) - 8.f, 11.f));
            l_acc += (p0 + p1) + (p2 + p3);
            f16x4 pk = { (f16)p0, (f16)p1, (f16)p2, (f16)p3 };
            *(f16x4*)&Pw[l15 * 136 + 16 * nt + quad * 4] = pk;   // wave-local, no barrier
        }
        // O(16q x 64d) += P @ V
#pragma unroll
        for (int ks = 0; ks < 4; ks++) {
            f16x8 pf = *(const f16x8*)&Pw[l15 * 136 + 32 * ks + quad * 8];
            const int vslot = ((ks * 4 + quad) ^ l15) * 8;
#pragma unroll
            for (int vt = 0; vt < 4; vt++) {
                f16x8 vf = *(const f16x8*)&Vsh[(vt * 16 + l15) * 128 + vslot];
                O[vt] = __builtin_amdgcn_mfma_f32_16x16x32_f16(pf, vf, O[vt], 0, 0, 0);
            }
        }
    }
    // finish l: sum quads, fetch per-O-row; normalize, fp16 store, stats
    l_acc += __shfl_xor(l_acc, 16, 64);
    l_acc += __shfl_xor(l_acc, 32, 64);
    float lb[4];
#pragma unroll
    for (int r = 0; r < 4; r++) lb[r] = 0.125f / __shfl(l_acc, quad * 4 + r, 64);
    float lsum = 0.f, lsq = 0.f;
#pragma unroll
    for (int t = 0; t < 4; t++)
#pragma unroll
        for (int r = 0; r < 4; r++) {
            float v = O[t][r] * lb[r];
            int gn = q0 + wid * 16 + quad * 4 + r;
            int gc = hh * DH + t * 16 + l15;
            out[((long)b * NTOK + gn) * 512 + gc] = (f16)v;
            lsum += v; lsq += v * v;
        }
#pragma unroll
    for (int d = 32; d >= 1; d >>= 1) { lsum += __shfl_xor(lsum, d, 64); lsq += __shfl_xor(lsq, d, 64); }
    if (lane == 0) { rbuf[wid] = lsum; rbuf[4 + wid] = lsq; }
    __syncthreads();
    if (tid == 0) {
        // spread over 64 slots x 64B: ~8 atomics/line (R10 lesson: one line = 14ns each serialized)
        float* sp = statsp + (id & 63) * 16;
        atomicAdd(&sp[b * 2], rbuf[0] + rbuf[1] + rbuf[2] + rbuf[3]);
        atomicAdd(&sp[b * 2 + 1], rbuf[4] + rbuf[5] + rbuf[6] + rbuf[7]);
    }
}

// ---- gemm2 + fused global-norm/FiLM on A; emits fp16 out1 + row stats -------
__global__ __launch_bounds__(256) void k_gemm2f(const f16* __restrict__ aout16, const float* __restrict__ statsp,
                                                const float* __restrict__ filmp,
                                                const f16* __restrict__ BT, const float* __restrict__ bias,
                                                f16* __restrict__ out1h, float* __restrict__ rstats) {
    __shared__ __attribute__((aligned(16))) f16 Ash[64 * 128];
    __shared__ __attribute__((aligned(16))) f16 Bsh[64 * 128];
    __shared__ float scsh[512], shsh[512];
    __shared__ float sred[2];
    const int tid = threadIdx.x;
    const int lane = tid & 63, wid = tid >> 6;
    const int quad = lane >> 4, l15 = lane & 15;
    const int m0 = blockIdx.x * 64, n0 = blockIdx.y * 64;
    const int wm = (wid >> 1) * 32, wn = (wid & 1) * 32;
    const int srow = lane >> 4, slot = lane & 15;
    const int b = m0 >> 10;
    if (tid < 64) {   // reduce the 64 spread stats slots (wave 0)
        float s = statsp[tid * 16 + b * 2];
        float q = statsp[tid * 16 + b * 2 + 1];
#pragma unroll
        for (int d = 32; d >= 1; d >>= 1) { s += __shfl_xor(s, d, 64); q += __shfl_xor(q, d, 64); }
        if (tid == 0) { sred[0] = s; sred[1] = q; }
    }
    __syncthreads();
    {   // per-column scale/shift table (batch-wide stats)
        float sum = sred[0], sq = sred[1];
        const float M = 524288.f;
        float mu = sum / M;
        float isd = rsqrtf((sq - sum * mu) / (M - 1.f));   // torch.std ddof=1
        for (int c = tid; c < 512; c += 256) {
            float sc = isd * filmp[b * 1024 + 512 + c];
            scsh[c] = sc;
            shsh[c] = filmp[b * 1024 + c] - mu * sc;
        }
    }
    __syncthreads();
    f32x4 acc[2][2] = {};
    for (int kk = 0; kk < 512; kk += 128) {
        if (kk) __syncthreads();
        const int j = slot ^ ((4 * wid + srow) & 7);   // constant per thread
        const int gcol = kk + 8 * j;
        float sc[8], sf[8];
        *(float4*)&sc[0] = *(const float4*)&scsh[gcol];
        *(float4*)&sc[4] = *(const float4*)&scsh[gcol + 4];
        *(float4*)&sf[0] = *(const float4*)&shsh[gcol];
        *(float4*)&sf[4] = *(const float4*)&shsh[gcol + 4];
#pragma unroll
        for (int c = 0; c < 4; c++) {
            int r = c * 16 + 4 * wid + srow;
            f16x8 v = *(const f16x8*)&aout16[(long)(m0 + r) * 512 + gcol];
            f16x8 y;
#pragma unroll
            for (int e = 0; e < 8; e++) y[e] = (f16)((float)v[e] * sc[e] + sf[e]);
            *(f16x8*)&Ash[(c * 16 + 4 * wid) * 128 + lane * 8] = y;
            glds16(&BT[(long)(n0 + r) * 512 + kk + 8 * j], &Bsh[(c * 16 + 4 * wid) * 128]);
        }
        __syncthreads();
#pragma unroll
        for (int ks = 0; ks < 4; ks++) {
            const int rslot = ((ks * 4 + quad) ^ (l15 & 7)) * 8;
            f16x8 af[2], bf[2];
#pragma unroll
            for (int t = 0; t < 2; t++) {
                af[t] = *(const f16x8*)&Ash[(wm + t * 16 + l15) * 128 + rslot];
                bf[t] = *(const f16x8*)&Bsh[(wn + t * 16 + l15) * 128 + rslot];
            }
#pragma unroll
            for (int mt = 0; mt < 2; mt++)
#pragma unroll
                for (int nt = 0; nt < 2; nt++)
                    acc[mt][nt] = __builtin_amdgcn_mfma_f32_16x16x32_f16(af[mt], bf[nt], acc[mt][nt], 0, 0, 0);
        }
    }
    // epilogue: +bias, fp16 store, per-row sum/sumsq partials -> rstats
#pragma unroll
    for (int mt = 0; mt < 2; mt++)
#pragma unroll
        for (int r = 0; r < 4; r++) {
            int gm = m0 + wm + mt * 16 + quad * 4 + r;
            float v0 = acc[mt][0][r] + bias[n0 + wn + l15];
            float v1 = acc[mt][1][r] + bias[n0 + wn + 16 + l15];
            out1h[(long)gm * 512 + n0 + wn + l15] = (f16)v0;
            out1h[(long)gm * 512 + n0 + wn + 16 + l15] = (f16)v1;
            float s = v0 + v1, q2 = v0 * v0 + v1 * v1;
#pragma unroll
            for (int d = 8; d >= 1; d >>= 1) { s += __shfl_xor(s, d, 16); q2 += __shfl_xor(q2, d, 16); }
            if (l15 == 0) {
                atomicAdd(&rstats[gm * 2], s);
                atomicAdd(&rstats[gm * 2 + 1], q2);
            }
        }
}

// ---- gemm3 with fused LayerNorm on A (row mu/inv + col g/b), GELU out -------
__global__ __launch_bounds__(256) void k_gemm3f(const f16* __restrict__ out1h, const float* __restrict__ rstats,
                                                const float* __restrict__ lng, const float* __restrict__ lnb,
                                                const f16* __restrict__ BT, const float* __restrict__ bias,
                                                f16* __restrict__ X4) {
    __shared__ __attribute__((aligned(16))) f16 Ash[64 * 128];
    __shared__ __attribute__((aligned(16))) f16 Bsh[64 * 128];
    __shared__ float musr[64], invsr[64], gsh[512], bsh[512];
    const int tid = threadIdx.x;
    const int lane = tid & 63, wid = tid >> 6;
    const int quad = lane >> 4, l15 = lane & 15;
    const int m0 = blockIdx.x * 64, n0 = blockIdx.y * 64;
    const int wm = (wid >> 1) * 32, wn = (wid & 1) * 32;
    const int srow = lane >> 4, slot = lane & 15;
    if (tid < 64) {
        float s = rstats[(m0 + tid) * 2], sq = rstats[(m0 + tid) * 2 + 1];
        float mu = s * (1.f / 512.f);
        float var = sq * (1.f / 512.f) - mu * mu;
        musr[tid] = mu;
        invsr[tid] = rsqrtf(var + 1e-5f);
    }
    for (int i = tid; i < 512; i += 256) { gsh[i] = lng[i]; bsh[i] = lnb[i]; }
    __syncthreads();
    f32x4 acc[2][2] = {};
    for (int kk = 0; kk < 512; kk += 128) {
        if (kk) __syncthreads();
        const int j = slot ^ ((4 * wid + srow) & 7);   // constant per thread
        const int gcol = kk + 8 * j;
        float gv[8], bv[8];
        *(float4*)&gv[0] = *(const float4*)&gsh[gcol];
        *(float4*)&gv[4] = *(const float4*)&gsh[gcol + 4];
        *(float4*)&bv[0] = *(const float4*)&bsh[gcol];
        *(float4*)&bv[4] = *(const float4*)&bsh[gcol + 4];
#pragma unroll
        for (int c = 0; c < 4; c++) {
            int r = c * 16 + 4 * wid + srow;
            f16x8 x = *(const f16x8*)&out1h[(long)(m0 + r) * 512 + gcol];
            float a = invsr[r], m = musr[r];
            f16x8 y;
#pragma unroll
            for (int e = 0; e < 8; e++) {
                float sc = a * gv[e];
                y[e] = (f16)((float)x[e] * sc + (bv[e] - m * sc));
            }
            *(f16x8*)&Ash[(c * 16 + 4 * wid) * 128 + lane * 8] = y;
            glds16(&BT[(long)(n0 + r) * 512 + kk + 8 * j], &Bsh[(c * 16 + 4 * wid) * 128]);
        }
        __syncthreads();
#pragma unroll
        for (int ks = 0; ks < 4; ks++) {
            const int rslot = ((ks * 4 + quad) ^ (l15 & 7)) * 8;
            f16x8 af[2], bf[2];
#pragma unroll
            for (int t = 0; t < 2; t++) {
                af[t] = *(const f16x8*)&Ash[(wm + t * 16 + l15) * 128 + rslot];
                bf[t] = *(const f16x8*)&Bsh[(wn + t * 16 + l15) * 128 + rslot];
            }
#pragma unroll
            for (int mt = 0; mt < 2; mt++)
#pragma unroll
                for (int nt = 0; nt < 2; nt++)
                    acc[mt][nt] = __builtin_amdgcn_mfma_f32_16x16x32_f16(af[mt], bf[nt], acc[mt][nt], 0, 0, 0);
        }
    }
#pragma unroll
    for (int mt = 0; mt < 2; mt++)
#pragma unroll
        for (int nt = 0; nt < 2; nt++)
#pragma unroll
            for (int r = 0; r < 4; r++) {
                int gm = m0 + wm + mt * 16 + quad * 4 + r;
                int gn = n0 + wn + nt * 16 + l15;
                float x = acc[mt][nt][r] + bias[gn];
                X4[(long)gm * 512 + gn] = (f16)(0.5f * x * (1.0f + erff(x * 0.70710678f)));
            }
}

// ---- 64x64-tile GEMM, BK=128, glds+swizzle (final: +bias fp32) --------------
__global__ __launch_bounds__(256) void k_gemm4(const f16* __restrict__ A, const f16* __restrict__ BT,
                                               const float* __restrict__ bias, float* __restrict__ dst) {
    __shared__ __attribute__((aligned(16))) f16 Ash[64 * 128];
    __shared__ __attribute__((aligned(16))) f16 Bsh[64 * 128];
    const int tid = threadIdx.x;
    const int lane = tid & 63, wid = tid >> 6;
    const int quad = lane >> 4, l15 = lane & 15;
    const int m0 = blockIdx.x * 64, n0 = blockIdx.y * 64;
    const int wm = (wid >> 1) * 32, wn = (wid & 1) * 32;
    const int srow = lane >> 4, slot = lane & 15;
    f32x4 acc[2][2] = {};
    for (int kk = 0; kk < 512; kk += 128) {
        if (kk) __syncthreads();
#pragma unroll
        for (int c = 0; c < 4; c++) {
            int r = c * 16 + 4 * wid + srow;
            int j = slot ^ (r & 7);
            glds16(&A[(long)(m0 + r) * 512 + kk + 8 * j], &Ash[(c * 16 + 4 * wid) * 128]);
            glds16(&BT[(long)(n0 + r) * 512 + kk + 8 * j], &Bsh[(c * 16 + 4 * wid) * 128]);
        }
        __syncthreads();
#pragma unroll
        for (int ks = 0; ks < 4; ks++) {
            const int rslot = ((ks * 4 + quad) ^ (l15 & 7)) * 8;
            f16x8 af[2], bf[2];
#pragma unroll
            for (int t = 0; t < 2; t++) {
                af[t] = *(const f16x8*)&Ash[(wm + t * 16 + l15) * 128 + rslot];
                bf[t] = *(const f16x8*)&Bsh[(wn + t * 16 + l15) * 128 + rslot];
            }
#pragma unroll
            for (int mt = 0; mt < 2; mt++)
#pragma unroll
                for (int nt = 0; nt < 2; nt++)
                    acc[mt][nt] = __builtin_amdgcn_mfma_f32_16x16x32_f16(af[mt], bf[nt], acc[mt][nt], 0, 0, 0);
        }
    }
#pragma unroll
    for (int mt = 0; mt < 2; mt++)
#pragma unroll
        for (int nt = 0; nt < 2; nt++)
#pragma unroll
            for (int r = 0; r < 4; r++) {
                int gm = m0 + wm + mt * 16 + quad * 4 + r;
                int gn = n0 + wn + nt * 16 + l15;
                dst[(long)gm * 512 + gn] = acc[mt][nt][r] + bias[gn];
            }
}

// ----------------------------------------------------------------------------
extern "C" void kernel_launch(void* const* d_in, const int* in_sizes, int n_in,
                              void* d_out, int out_size, void* d_ws, size_t ws_size,
                              hipStream_t stream) {
    const float* con      = (const float*)d_in[0];
    const float* diff     = (const float*)d_in[1];
    const float* temb     = (const float*)d_in[2];
    const float* ln_con_g = (const float*)d_in[3];
    const float* ln_con_b = (const float*)d_in[4];
    const float* ln_dif_g = (const float*)d_in[5];
    const float* ln_dif_b = (const float*)d_in[6];
    const float* wq       = (const float*)d_in[7];
    const float* wk       = (const float*)d_in[8];
    const float* wv       = (const float*)d_in[9];
    const float* w_out    = (const float*)d_in[10];
    const float* b_out    = (const float*)d_in[11];
    const float* w_emd1   = (const float*)d_in[12];
    const float* b_emd1   = (const float*)d_in[13];
    const float* w_emd2   = (const float*)d_in[14];
    const float* b_emd2   = (const float*)d_in[15];
    const float* mlp_ln_g = (const float*)d_in[16];
    const float* mlp_ln_b = (const float*)d_in[17];
    const float* mlp_w1   = (const float*)d_in[18];
    const float* mlp_b1   = (const float*)d_in[19];
    const float* mlp_w2   = (const float*)d_in[20];
    const float* mlp_b2   = (const float*)d_in[21];
    float* outp = (float*)d_out;

    char* ws = (char*)d_ws;
    size_t off = 0;
    auto alloc = [&](size_t bytes) { void* p = ws + off; off += (bytes + 255) & ~(size_t)255; return p; };
    f16*   A16   = (f16*)alloc((size_t)ROWS * 512 * 2);   // LN(diff)
    f16*   C16   = (f16*)alloc((size_t)ROWS * 512 * 2);   // LN(con); later X4
    f16*   Qh    = (f16*)alloc((size_t)ROWS * 512 * 2);   // later out1h
    f16*   Kf    = (f16*)alloc((size_t)ROWS * 512 * 2);
    f16*   Vt    = (f16*)alloc((size_t)ROWS * 512 * 2);
    f16*   aout16= (f16*)alloc((size_t)ROWS * 512 * 2);   // attn out (pre-norm), fp16
    f16*   wqT   = (f16*)alloc(512 * 512 * 2);
    f16*   wkT   = (f16*)alloc(512 * 512 * 2);
    f16*   wvT   = (f16*)alloc(512 * 512 * 2);
    f16*   woT   = (f16*)alloc(512 * 512 * 2);
    f16*   w1T   = (f16*)alloc(512 * 512 * 2);
    f16*   w2T   = (f16*)alloc(512 * 512 * 2);
    float* tbacc = (float*)alloc(4 * 1024 * 4);
    float* filmp = (float*)alloc(4 * 1024 * 4);
    float* statsp= (float*)alloc(64 * 16 * 4);            // 64 spread slots x 64B
    float* rstats= (float*)alloc(ROWS * 2 * 4);
    f16*   out1h = Qh;    // overlay (Qh dead after attn)
    f16*   X4    = C16;   // overlay (C16 dead after qkv)

    PrepArgs pa;
    pa.src[0] = wq;  pa.src[1] = wk;  pa.src[2] = wv;
    pa.src[3] = w_out; pa.src[4] = mlp_w1; pa.src[5] = mlp_w2;
    pa.dst[0] = wqT; pa.dst[1] = wkT; pa.dst[2] = wvT;
    pa.dst[3] = woT; pa.dst[4] = w1T; pa.dst[5] = w2T;

    k_pre<<<dim3(3632), dim3(256), 0, stream>>>(pa, statsp, b_emd1, b_emd2, tbacc, filmp, rstats,
                                                diff, ln_dif_g, ln_dif_b, A16,
                                                con, ln_con_g, ln_con_b, C16);
    k_qkv<<<dim3(832), dim3(256), 0, stream>>>(A16, C16, wqT, wkT, wvT, Qh, Kf, Vt,
                                               temb, w_emd1, tbacc);
    k_attn<<<dim3(640), dim3(256), 0, stream>>>(Qh, Kf, Vt, aout16, statsp,
                                                tbacc, w_emd2, filmp);
    k_gemm2f<<<dim3(64, 8), dim3(256), 0, stream>>>(aout16, statsp, filmp, woT, b_out, out1h, rstats);
    k_gemm3f<<<dim3(64, 8), dim3(256), 0, stream>>>(out1h, rstats, mlp_ln_g, mlp_ln_b, w1T, mlp_b1, X4);
    k_gemm4<<<dim3(64, 8), dim3(256), 0, stream>>>(X4, w2T, mlp_b2, outp);
}